// Round 4
// baseline (654.924 us; speedup 1.0000x reference)
//
#include <hip/hip_runtime.h>
#include <hip/hip_bf16.h>
#include <math.h>

#define T_LEN 4096
#define BATCH 16

// ---------------------------------------------------------------------------
// k_gcn: adapter + node projections + A_HAT propagation + relu + node-mean.
// (unchanged from R8)
// ---------------------------------------------------------------------------
__global__ __launch_bounds__(256) void k_gcn(
    const float* __restrict__ x,      // [B][T][218]
    const float* __restrict__ gcn_w,  // [18][64]
    float* __restrict__ hp)           // [B][64][T]
{
    __shared__ float xt[218 * 36];
    __shared__ float wg[18 * 64];

    const int b   = blockIdx.y;
    const int t0  = blockIdx.x * 32;
    const int tid = threadIdx.x;

    const float* xb = x + ((long)b * T_LEN + t0) * 218;
    #pragma unroll 1
    for (int i = tid; i < 32 * 218; i += 256) {
        const int t = i / 218;
        const int c = i - 218 * t;
        xt[c * 36 + t] = xb[i];
    }
    for (int i = tid; i < 18 * 64; i += 256) wg[i] = gcn_w[i];
    __syncthreads();

    const int dg = tid >> 4;
    const int tt = tid & 15;
    const int d0 = dg * 4;
    const int tb = tt * 2;

    float wr[10][4];
    #pragma unroll
    for (int c = 0; c < 10; ++c)
        *(float4*)wr[c] = *(const float4*)(gcn_w + c * 64 + d0);

    const float cP = 1.0f / 6.0f;
    const float cS = 0.23570226039551584f;   // 1/sqrt(18)
    const float c3 = 1.0f / 3.0f;
    const float cT = 0.4082482904638631f;    // 1/sqrt(6)
    const float cH = 0.5f;

    float h0[4][2];
    #pragma unroll
    for (int di = 0; di < 4; ++di) h0[di][0] = h0[di][1] = 0.f;
    #pragma unroll 1
    for (int c = 0; c < 18; ++c) {
        float wv[4];
        *(float4*)wv = *(const float4*)(&wg[c * 64 + d0]);
        const float2 xv = *(const float2*)(&xt[c * 36 + tb]);
        #pragma unroll
        for (int di = 0; di < 4; ++di) {
            h0[di][0] = fmaf(wv[di], xv.x, h0[di][0]);
            h0[di][1] = fmaf(wv[di], xv.y, h0[di][1]);
        }
    }

    float pool[4][2], star[4][2];
    #pragma unroll
    for (int di = 0; di < 4; ++di) {
        pool[di][0] = pool[di][1] = 0.f;
        star[di][0] = star[di][1] = 0.f;
    }

    #pragma unroll 1
    for (int f = 0; f < 5; ++f) {
        float hn[4][2], hprev[4][2], s12[4][2];
        #pragma unroll
        for (int n = 0; n < 4; ++n) {
            #pragma unroll
            for (int di = 0; di < 4; ++di) hn[di][0] = hn[di][1] = 0.f;
            const int cb = 18 + 10 * (4 * f + n);
            #pragma unroll
            for (int c = 0; c < 10; ++c) {
                const float2 xv = *(const float2*)(&xt[(cb + c) * 36 + tb]);
                #pragma unroll
                for (int di = 0; di < 4; ++di) {
                    hn[di][0] = fmaf(wr[c][di], xv.x, hn[di][0]);
                    hn[di][1] = fmaf(wr[c][di], xv.y, hn[di][1]);
                }
            }
            #pragma unroll
            for (int di = 0; di < 4; ++di)
                #pragma unroll
                for (int ti = 0; ti < 2; ++ti) {
                    const float h = hn[di][ti];
                    if (n == 0) {
                        star[di][ti] += h;
                        s12[di][ti] = h;
                        hprev[di][ti] = h;
                    } else if (n == 1) {
                        const float pa = fmaf(cS, h0[di][ti], c3 * (s12[di][ti] + h));
                        pool[di][ti] += fmaxf(pa, 0.f);
                        s12[di][ti] += h;
                        hprev[di][ti] = h;
                    } else if (n == 2) {
                        const float pb = c3 * (s12[di][ti] + h);
                        pool[di][ti] += fmaxf(pb, 0.f);
                        s12[di][ti] = hprev[di][ti] + h;
                        hprev[di][ti] = h;
                    } else {
                        const float pc = fmaf(cT, h, c3 * s12[di][ti]);
                        const float pe = fmaf(cT, hprev[di][ti], cH * h);
                        pool[di][ti] += fmaxf(pc, 0.f) + fmaxf(pe, 0.f);
                    }
                }
        }
    }

    float* hpb = hp + (long)b * 64 * T_LEN + t0 + tb;
    #pragma unroll
    for (int di = 0; di < 4; ++di) {
        float2 r;
        const float p0a = fmaf(cP, h0[di][0], cS * star[di][0]);
        const float p0b = fmaf(cP, h0[di][1], cS * star[di][1]);
        r.x = (pool[di][0] + fmaxf(p0a, 0.f)) * (1.0f / 21.0f);
        r.y = (pool[di][1] + fmaxf(p0b, 0.f)) * (1.0f / 21.0f);
        *(float2*)(hpb + (long)(d0 + di) * T_LEN) = r;
    }
}

// ---------------------------------------------------------------------------
// k_mstcn R12: windows stream from GLOBAL, not LDS.
// R10/R11 post-mortem: hipcc refuses to software-pipeline ds_read across
// the c-loop (sinks to just-before-use regardless of register budget;
// VGPR stuck at 92 both rounds) -> the loop-carried ds_read->lgkmcnt->FMA
// chain is unbreakable at source level for LDS. But the 17 global weight
// loads have been pipelined fine all along (vmcnt machinery, hoisted).
// So: read the 9xfloat4 window per c straight from global. The 16 tt
// lanes' windows overlap within ~512B per row -> L1/L2-served; x-tile
// staging + its syncthreads deleted; LDS drops 25.6->17.4 KB.
// t0==0 boundary: block-uniform clamped/zero path (no padding, no extra
// workspace). Falsifier: if dur >= ~110us, per-wave load latency is not
// the stall for either memory type -> pivot to split-c 4-wave.
// ---------------------------------------------------------------------------
template <bool FINAL>
__global__ __launch_bounds__(128, 2) void k_mstcn(
    const float* __restrict__ in,   // [B][64][T]
    const float* __restrict__ ws, const float* __restrict__ bs,
    const float* __restrict__ wm, const float* __restrict__ bm,
    const float* __restrict__ wl, const float* __restrict__ bl,
    const float* __restrict__ wo, const float* __restrict__ bo,
    float* __restrict__ out,        // [B][64][T]  (FINAL=false)
    const float* __restrict__ wd,   // [64][32]    (FINAL=true)
    const float* __restrict__ bd,   // [32]
    float* __restrict__ outp)       // [B][32]     (FINAL=true)
{
    __shared__ float smem[64 * 68]; // h tile [64 ch][64 t] stride 68

    const int b   = blockIdx.y;
    const int t0  = blockIdx.x * 64;
    const int tid = threadIdx.x;
    const int cjg = tid >> 4;        // 0..7 composite j-group
    const int tt  = tid & 15;        // 4 t at tt*4

    const float* inb = in + (long)b * 64 * T_LEN;
    const bool BND = (t0 == 0);      // block-uniform boundary flag

    // ---- conv phase ----
    const int js = 2 * cjg;          // s channels (concat 0..15)
    const int jm = 2 * cjg;          // m channels (concat 16..31)
    const int jl = 4 * cjg;          // l channels (concat 32..63)

    float as[2][4], am[2][4], al[4][4];
    {
        const float2 b2s = *(const float2*)(bs + js);
        const float2 b2m = *(const float2*)(bm + jm);
        float b4l[4];
        *(float4*)b4l = *(const float4*)(bl + jl);
        #pragma unroll
        for (int i = 0; i < 4; ++i) {
            as[0][i] = b2s.x; as[1][i] = b2s.y;
            am[0][i] = b2m.x; am[1][i] = b2m.y;
            #pragma unroll
            for (int j = 0; j < 4; ++j) al[j][i] = b4l[j];
        }
    }

    float2 wsr[3], wmr[5];
    float  wlr[9][4];
    #pragma unroll
    for (int k = 0; k < 3; ++k) wsr[k] = *(const float2*)(ws + (k * 64) * 16 + js);
    #pragma unroll
    for (int k = 0; k < 5; ++k) wmr[k] = *(const float2*)(wm + (k * 64) * 16 + jm);
    #pragma unroll
    for (int k = 0; k < 9; ++k) *(float4*)wlr[k] = *(const float4*)(wl + (k * 64) * 32 + jl);

    // window double buffer: winA holds current c, winB prefetches c+1.
    // win[q] = x[c][t0 + tt*4 + q - 32]
    float winA[36], winB[36];

#define LOADWIN(W, CC) do {                                              \
        const float* rc_ = inb + (long)(CC) * T_LEN;                     \
        if (!BND) {                                                      \
            const float* rp_ = rc_ + (t0 - 32 + tt * 4);                 \
            _Pragma("unroll")                                            \
            for (int m_ = 0; m_ < 9; ++m_)                               \
                *(float4*)(&(W)[4 * m_]) = *(const float4*)(rp_ + 4 * m_); \
        } else {                                                         \
            _Pragma("unroll")                                            \
            for (int m_ = 0; m_ < 9; ++m_) {                             \
                const int off_ = tt * 4 - 32 + 4 * m_;                   \
                float4 v_ = *(const float4*)(rc_ + (off_ > 0 ? off_ : 0)); \
                if (off_ < 0) v_ = make_float4(0.f, 0.f, 0.f, 0.f);      \
                *(float4*)(&(W)[4 * m_]) = v_;                           \
            }                                                            \
        }                                                                \
    } while (0)

#define COMPUTE(W, C) do {                                               \
        const int cn_ = ((C) < 63) ? (C) + 1 : 63;                       \
        _Pragma("unroll")                                                \
        for (int k = 0; k < 3; ++k) {                                    \
            _Pragma("unroll")                                            \
            for (int i = 0; i < 4; ++i) {                                \
                const float v = (W)[30 + i + k];                         \
                as[0][i] = fmaf(wsr[k].x, v, as[0][i]);                  \
                as[1][i] = fmaf(wsr[k].y, v, as[1][i]);                  \
            }                                                            \
            wsr[k] = *(const float2*)(ws + (k * 64 + cn_) * 16 + js);    \
        }                                                                \
        _Pragma("unroll")                                                \
        for (int k = 0; k < 5; ++k) {                                    \
            _Pragma("unroll")                                            \
            for (int i = 0; i < 4; ++i) {                                \
                const float v = (W)[24 + i + 2 * k];                     \
                am[0][i] = fmaf(wmr[k].x, v, am[0][i]);                  \
                am[1][i] = fmaf(wmr[k].y, v, am[1][i]);                  \
            }                                                            \
            wmr[k] = *(const float2*)(wm + (k * 64 + cn_) * 16 + jm);    \
        }                                                                \
        _Pragma("unroll")                                                \
        for (int k = 0; k < 9; ++k) {                                    \
            _Pragma("unroll")                                            \
            for (int i = 0; i < 4; ++i) {                                \
                const float v = (W)[i + 4 * k];                          \
                al[0][i] = fmaf(wlr[k][0], v, al[0][i]);                 \
                al[1][i] = fmaf(wlr[k][1], v, al[1][i]);                 \
                al[2][i] = fmaf(wlr[k][2], v, al[2][i]);                 \
                al[3][i] = fmaf(wlr[k][3], v, al[3][i]);                 \
            }                                                            \
            *(float4*)wlr[k] = *(const float4*)(wl + (k * 64 + cn_) * 32 + jl); \
        }                                                                \
    } while (0)

    LOADWIN(winA, 0);
    #pragma unroll 1
    for (int c = 0; c < 64; c += 2) {
        // prefetch window c+1 into winB, then compute c from winA
        LOADWIN(winB, c + 1);
        COMPUTE(winA, c);
        // prefetch window c+2 into winA (clamped dummy on last iter)
        LOADWIN(winA, (c + 2 < 64) ? c + 2 : 63);
        COMPUTE(winB, c + 1);
    }

#undef LOADWIN
#undef COMPUTE

    // ---- relu + stage h [64 j][64 t] stride 68 ----
    // (no leading syncthreads needed: smem untouched so far; disjoint writes)
    #pragma unroll
    for (int j = 0; j < 2; ++j)
        *(float4*)(&smem[(js + j) * 68 + tt * 4]) =
            make_float4(fmaxf(as[j][0], 0.f), fmaxf(as[j][1], 0.f),
                        fmaxf(as[j][2], 0.f), fmaxf(as[j][3], 0.f));
    #pragma unroll
    for (int j = 0; j < 2; ++j)
        *(float4*)(&smem[(16 + jm + j) * 68 + tt * 4]) =
            make_float4(fmaxf(am[j][0], 0.f), fmaxf(am[j][1], 0.f),
                        fmaxf(am[j][2], 0.f), fmaxf(am[j][3], 0.f));
    #pragma unroll
    for (int j = 0; j < 4; ++j)
        *(float4*)(&smem[(32 + jl + j) * 68 + tt * 4]) =
            make_float4(fmaxf(al[j][0], 0.f), fmaxf(al[j][1], 0.f),
                        fmaxf(al[j][2], 0.f), fmaxf(al[j][3], 0.f));
    __syncthreads();

    // ---- conv_out 64->64 (no relu): thread = 8 d x 4 t ----
    const int d0 = cjg * 8;
    float o[8][4];
    {
        float bv[8];
        *(float4*)(&bv[0]) = *(const float4*)(bo + d0);
        *(float4*)(&bv[4]) = *(const float4*)(bo + d0 + 4);
        #pragma unroll
        for (int di = 0; di < 8; ++di)
            #pragma unroll
            for (int i = 0; i < 4; ++i) o[di][i] = bv[di];
    }
    #pragma unroll 4
    for (int j = 0; j < 64; ++j) {
        float wv[8], hv[4];
        *(float4*)(&wv[0]) = *(const float4*)(wo + j * 64 + d0);
        *(float4*)(&wv[4]) = *(const float4*)(wo + j * 64 + d0 + 4);
        *(float4*)hv       = *(const float4*)(&smem[j * 68 + tt * 4]);
        #pragma unroll
        for (int di = 0; di < 8; ++di)
            #pragma unroll
            for (int i = 0; i < 4; ++i)
                o[di][i] = fmaf(wv[di], hv[i], o[di][i]);
    }

    if (!FINAL) {
        float* ob = out + (long)b * 64 * T_LEN + t0 + tt * 4;
        #pragma unroll
        for (int di = 0; di < 8; ++di)
            *(float4*)(ob + (long)(d0 + di) * T_LEN) =
                make_float4(o[di][0], o[di][1], o[di][2], o[di][3]);
    } else {
        // ---- stage t2 [64 d][64 t], then dense 64->32 + tanh + mean ----
        __syncthreads();
        #pragma unroll
        for (int di = 0; di < 8; ++di)
            *(float4*)(&smem[(d0 + di) * 68 + tt * 4]) =
                make_float4(o[di][0], o[di][1], o[di][2], o[di][3]);
        __syncthreads();

        const int eg = tid >> 5;       // 4 groups x 8 e
        const int e0 = eg * 8;
        const int tl = tid & 31;       // 2 t at tl*2
        float fa[8], fb[8];
        *(float4*)(&fa[0]) = *(const float4*)(bd + e0);
        *(float4*)(&fa[4]) = *(const float4*)(bd + e0 + 4);
        #pragma unroll
        for (int e = 0; e < 8; ++e) fb[e] = fa[e];

        #pragma unroll 4
        for (int d = 0; d < 64; ++d) {
            const float2 hv = *(const float2*)(&smem[d * 68 + tl * 2]);
            float wv[8];
            *(float4*)(&wv[0]) = *(const float4*)(wd + d * 32 + e0);
            *(float4*)(&wv[4]) = *(const float4*)(wd + d * 32 + e0 + 4);
            #pragma unroll
            for (int e = 0; e < 8; ++e) {
                fa[e] = fmaf(wv[e], hv.x, fa[e]);
                fb[e] = fmaf(wv[e], hv.y, fb[e]);
            }
        }
        #pragma unroll
        for (int e = 0; e < 8; ++e) {
            float v = (tanhf(fa[e]) + tanhf(fb[e])) * (1.0f / (float)T_LEN);
            v += __shfl_down(v, 16, 32);
            v += __shfl_down(v, 8, 32);
            v += __shfl_down(v, 4, 32);
            v += __shfl_down(v, 2, 32);
            v += __shfl_down(v, 1, 32);
            if (tl == 0) atomicAdd(&outp[b * 32 + e0 + e], v);
        }
    }
}

extern "C" void kernel_launch(void* const* d_in, const int* in_sizes, int n_in,
                              void* d_out, int out_size, void* d_ws, size_t ws_size,
                              hipStream_t stream) {
    const float* x     = (const float*)d_in[0];
    const float* gcn_w = (const float*)d_in[1];
    const float* wd    = (const float*)d_in[2];
    const float* bd    = (const float*)d_in[3];
    const float* t1_ws = (const float*)d_in[4];
    const float* t1_bs = (const float*)d_in[5];
    const float* t1_wm = (const float*)d_in[6];
    const float* t1_bm = (const float*)d_in[7];
    const float* t1_wl = (const float*)d_in[8];
    const float* t1_bl = (const float*)d_in[9];
    const float* t1_wo = (const float*)d_in[10];
    const float* t1_bo = (const float*)d_in[11];
    const float* t2_ws = (const float*)d_in[12];
    const float* t2_bs = (const float*)d_in[13];
    const float* t2_wm = (const float*)d_in[14];
    const float* t2_bm = (const float*)d_in[15];
    const float* t2_wl = (const float*)d_in[16];
    const float* t2_bl = (const float*)d_in[17];
    const float* t2_wo = (const float*)d_in[18];
    const float* t2_bo = (const float*)d_in[19];

    float* b0 = (float*)d_ws;                          // [16][64][4096]
    float* b1 = b0 + (size_t)BATCH * 64 * T_LEN;       // [16][64][4096]

    hipMemsetAsync(d_out, 0, (size_t)out_size * sizeof(float), stream);

    k_gcn<<<dim3(T_LEN / 32, BATCH), 256, 0, stream>>>(x, gcn_w, b0);

    k_mstcn<false><<<dim3(T_LEN / 64, BATCH), 128, 0, stream>>>(
        b0, t1_ws, t1_bs, t1_wm, t1_bm, t1_wl, t1_bl, t1_wo, t1_bo,
        b1, nullptr, nullptr, nullptr);

    k_mstcn<true><<<dim3(T_LEN / 64, BATCH), 128, 0, stream>>>(
        b1, t2_ws, t2_bs, t2_wm, t2_bm, t2_wl, t2_bl, t2_wo, t2_bo,
        nullptr, wd, bd, (float*)d_out);
}

// Round 5
// 276.885 us; speedup vs baseline: 2.3653x; 2.3653x over previous
//
#include <hip/hip_runtime.h>
#include <hip/hip_bf16.h>
#include <math.h>

#define T_LEN 4096
#define BATCH 16

typedef _Float16 f16;
typedef _Float16 f16x2 __attribute__((ext_vector_type(2)));
typedef _Float16 f16x8 __attribute__((ext_vector_type(8)));
typedef float f32x4 __attribute__((ext_vector_type(4)));

// Packed MFMA A-fragments, hi/lo split-f16. 124 logical frags:
// per layer (60): S[k(3)][q(2)]=0..5, M[k(5)][q(2)]=6..15,
// L[k(9)][q(2)][ms(2)]=16..51, O[ms(4)][kh(2)]=52..59; layer stride 60.
// D (dense 64->32): 120..123 = [ms(2)][kh(2)].
// Frag f: hi at f*1024 + lane*8, lo at f*1024 + 512 + lane*8 (f16 units).
// A[m][k]: m = lane&15, k = (lane>>4)*8 + j  (16x16x32 f16 A-layout).
__device__ __align__(16) f16 g_pk[124 * 1024];

// ---------------------------------------------------------------------------
// k_pack: one-time weight repack -> MFMA fragments (hi/lo f16).
// ---------------------------------------------------------------------------
__global__ void k_pack(
    const float* __restrict__ ws1, const float* __restrict__ wm1,
    const float* __restrict__ wl1, const float* __restrict__ wo1,
    const float* __restrict__ ws2, const float* __restrict__ wm2,
    const float* __restrict__ wl2, const float* __restrict__ wo2,
    const float* __restrict__ wd)
{
    const int g = blockIdx.x;          // 0..123 logical frag
    const int tid = threadIdx.x;
    #pragma unroll
    for (int u = 0; u < 2; ++u) {
        const int e = tid * 2 + u;     // 0..511
        const int lane = e >> 3, j = e & 7;
        const int m = lane & 15, k = (lane >> 4) * 8 + j;
        float w;
        if (g < 120) {
            const int layer = g / 60, r0 = g % 60;
            const float* pws = layer ? ws2 : ws1;
            const float* pwm = layer ? wm2 : wm1;
            const float* pwl = layer ? wl2 : wl1;
            const float* pwo = layer ? wo2 : wo1;
            if (r0 < 6) {
                const int kp = r0 >> 1, q = r0 & 1;
                w = pws[(kp * 64 + q * 32 + k) * 16 + m];        // ws[k][c][j]
            } else if (r0 < 16) {
                const int r = r0 - 6, kp = r >> 1, q = r & 1;
                w = pwm[(kp * 64 + q * 32 + k) * 16 + m];
            } else if (r0 < 52) {
                const int r = r0 - 16, kp = r >> 2, q = (r >> 1) & 1, ms = r & 1;
                w = pwl[(kp * 64 + q * 32 + k) * 32 + ms * 16 + m];
            } else {
                const int r = r0 - 52, ms = r >> 1, kh = r & 1;
                w = pwo[(kh * 32 + k) * 64 + ms * 16 + m];       // wo[j][d] -> A[d][j]
            }
        } else {
            const int r = g - 120, ms = r >> 1, kh = r & 1;
            w = wd[(kh * 32 + k) * 32 + ms * 16 + m];            // wd[d][e] -> A[e][d]
        }
        const f16 hi = (f16)w;
        const f16 lo = (f16)(w - (float)hi);
        g_pk[g * 1024 + e] = hi;
        g_pk[g * 1024 + 512 + e] = lo;
    }
}

// ---------------------------------------------------------------------------
// k_gcn: unchanged from R8.
// ---------------------------------------------------------------------------
__global__ __launch_bounds__(256) void k_gcn(
    const float* __restrict__ x,      // [B][T][218]
    const float* __restrict__ gcn_w,  // [18][64]
    float* __restrict__ hp)           // [B][64][T]
{
    __shared__ float xt[218 * 36];
    __shared__ float wg[18 * 64];

    const int b   = blockIdx.y;
    const int t0  = blockIdx.x * 32;
    const int tid = threadIdx.x;

    const float* xb = x + ((long)b * T_LEN + t0) * 218;
    #pragma unroll 1
    for (int i = tid; i < 32 * 218; i += 256) {
        const int t = i / 218;
        const int c = i - 218 * t;
        xt[c * 36 + t] = xb[i];
    }
    for (int i = tid; i < 18 * 64; i += 256) wg[i] = gcn_w[i];
    __syncthreads();

    const int dg = tid >> 4;
    const int tt = tid & 15;
    const int d0 = dg * 4;
    const int tb = tt * 2;

    float wr[10][4];
    #pragma unroll
    for (int c = 0; c < 10; ++c)
        *(float4*)wr[c] = *(const float4*)(gcn_w + c * 64 + d0);

    const float cP = 1.0f / 6.0f;
    const float cS = 0.23570226039551584f;   // 1/sqrt(18)
    const float c3 = 1.0f / 3.0f;
    const float cT = 0.4082482904638631f;    // 1/sqrt(6)
    const float cH = 0.5f;

    float h0[4][2];
    #pragma unroll
    for (int di = 0; di < 4; ++di) h0[di][0] = h0[di][1] = 0.f;
    #pragma unroll 1
    for (int c = 0; c < 18; ++c) {
        float wv[4];
        *(float4*)wv = *(const float4*)(&wg[c * 64 + d0]);
        const float2 xv = *(const float2*)(&xt[c * 36 + tb]);
        #pragma unroll
        for (int di = 0; di < 4; ++di) {
            h0[di][0] = fmaf(wv[di], xv.x, h0[di][0]);
            h0[di][1] = fmaf(wv[di], xv.y, h0[di][1]);
        }
    }

    float pool[4][2], star[4][2];
    #pragma unroll
    for (int di = 0; di < 4; ++di) {
        pool[di][0] = pool[di][1] = 0.f;
        star[di][0] = star[di][1] = 0.f;
    }

    #pragma unroll 1
    for (int f = 0; f < 5; ++f) {
        float hn[4][2], hprev[4][2], s12[4][2];
        #pragma unroll
        for (int n = 0; n < 4; ++n) {
            #pragma unroll
            for (int di = 0; di < 4; ++di) hn[di][0] = hn[di][1] = 0.f;
            const int cb = 18 + 10 * (4 * f + n);
            #pragma unroll
            for (int c = 0; c < 10; ++c) {
                const float2 xv = *(const float2*)(&xt[(cb + c) * 36 + tb]);
                #pragma unroll
                for (int di = 0; di < 4; ++di) {
                    hn[di][0] = fmaf(wr[c][di], xv.x, hn[di][0]);
                    hn[di][1] = fmaf(wr[c][di], xv.y, hn[di][1]);
                }
            }
            #pragma unroll
            for (int di = 0; di < 4; ++di)
                #pragma unroll
                for (int ti = 0; ti < 2; ++ti) {
                    const float h = hn[di][ti];
                    if (n == 0) {
                        star[di][ti] += h;
                        s12[di][ti] = h;
                        hprev[di][ti] = h;
                    } else if (n == 1) {
                        const float pa = fmaf(cS, h0[di][ti], c3 * (s12[di][ti] + h));
                        pool[di][ti] += fmaxf(pa, 0.f);
                        s12[di][ti] += h;
                        hprev[di][ti] = h;
                    } else if (n == 2) {
                        const float pb = c3 * (s12[di][ti] + h);
                        pool[di][ti] += fmaxf(pb, 0.f);
                        s12[di][ti] = hprev[di][ti] + h;
                        hprev[di][ti] = h;
                    } else {
                        const float pc = fmaf(cT, h, c3 * s12[di][ti]);
                        const float pe = fmaf(cT, hprev[di][ti], cH * h);
                        pool[di][ti] += fmaxf(pc, 0.f) + fmaxf(pe, 0.f);
                    }
                }
        }
    }

    float* hpb = hp + (long)b * 64 * T_LEN + t0 + tb;
    #pragma unroll
    for (int di = 0; di < 4; ++di) {
        float2 r;
        const float p0a = fmaf(cP, h0[di][0], cS * star[di][0]);
        const float p0b = fmaf(cP, h0[di][1], cS * star[di][1]);
        r.x = (pool[di][0] + fmaxf(p0a, 0.f)) * (1.0f / 21.0f);
        r.y = (pool[di][1] + fmaxf(p0b, 0.f)) * (1.0f / 21.0f);
        *(float2*)(hpb + (long)(d0 + di) * T_LEN) = r;
    }
}

// ---------------------------------------------------------------------------
// k_mstcn R13: MFMA rewrite (split-f16 hi/lo, 3 mfma per logical product).
// R9-R12 post-mortem: VALU-busy-time constant ~41-47us across 4 structural
// variants while dur 112-268us -> the fat per-c VALU loop is latency-convoy
// bound no matter which pipe feeds it, and hipcc won't pipeline it. So move
// the math to the idle MFMA pipe: branches/conv_out/dense are all GEMMs.
// Block = 256 thr = 4 waves, wave owns 16 t. x staged once as transposed
// hi/lo f16 planes [96 t][72 c-pitch] (16B-aligned rows); weights stream as
// pre-packed fragments from g_pk. ~70 LDS b128 reads/wave total (vs 576).
// Precision: split-f16 -> ~2^-22 rel error (~1e-5 abs at outputs).
// ---------------------------------------------------------------------------
template <bool FINAL>
__global__ __launch_bounds__(256, 3) void k_mstcn(
    const float* __restrict__ in,   // [B][64][T]
    const float* __restrict__ bs, const float* __restrict__ bm,
    const float* __restrict__ bl, const float* __restrict__ bo,
    int pkoff,                      // layer * 61440 (f16 units)
    float* __restrict__ out,        // [B][64][T]  (FINAL=false)
    const float* __restrict__ bd,   // [32]        (FINAL=true)
    float* __restrict__ outp)       // [B][32]     (FINAL=true)
{
    // f16 units: XH=0(96x72), XL=6912, HH=13824(64x72), HL=18432; total 23040
    __shared__ __align__(16) f16 lds[23040];

    const int b   = blockIdx.y;
    const int t0  = blockIdx.x * 64;
    const int tid = threadIdx.x;
    const float* inb = in + (long)b * 64 * T_LEN;

    // ---- stage x window [t0-32, t0+64) -> transposed hi/lo planes ----
    {
        const int c0 = (tid >> 3) * 2;      // c pair
        const int tq = (tid & 7) * 12;      // 12 t per thread
        float v0[12], v1[12];
        if (t0 != 0 || tq >= 32) {
            const float* r0 = inb + (long)c0 * T_LEN + (t0 - 32 + tq);
            const float* r1 = r0 + T_LEN;
            #pragma unroll
            for (int mq = 0; mq < 3; ++mq) {
                *(float4*)(v0 + 4 * mq) = *(const float4*)(r0 + 4 * mq);
                *(float4*)(v1 + 4 * mq) = *(const float4*)(r1 + 4 * mq);
            }
        } else {
            #pragma unroll
            for (int i = 0; i < 12; ++i) {
                const int tg = tq + i - 32;
                v0[i] = (tg >= 0) ? inb[(long)c0 * T_LEN + tg] : 0.f;
                v1[i] = (tg >= 0) ? inb[(long)(c0 + 1) * T_LEN + tg] : 0.f;
            }
        }
        #pragma unroll
        for (int i = 0; i < 12; ++i) {
            const f16 h0 = (f16)v0[i], h1 = (f16)v1[i];
            const f16 l0 = (f16)(v0[i] - (float)h0), l1 = (f16)(v1[i] - (float)h1);
            const int row = tq + i;
            *(f16x2*)(&lds[row * 72 + c0])        = (f16x2){h0, h1};
            *(f16x2*)(&lds[6912 + row * 72 + c0]) = (f16x2){l0, l1};
        }
    }
    __syncthreads();

    const int lane = tid & 63, wid = tid >> 6;
    const int l15 = lane & 15, lg = lane >> 4;
    const int tw  = wid * 16;
    const f16* pk = g_pk + pkoff;
    const int la8 = lane * 8;

#define MFMA3(ACC, PA, BH, BL) do {                                        \
        const f16x8 ah_ = *(const f16x8*)(PA);                             \
        const f16x8 al_ = *(const f16x8*)((PA) + 512);                     \
        ACC = __builtin_amdgcn_mfma_f32_16x16x32_f16(ah_, BH, ACC, 0,0,0); \
        ACC = __builtin_amdgcn_mfma_f32_16x16x32_f16(ah_, BL, ACC, 0,0,0); \
        ACC = __builtin_amdgcn_mfma_f32_16x16x32_f16(al_, BH, ACC, 0,0,0); \
    } while (0)

    // ---- GEMM1: branches.  C[j][t]: row j = lg*4+reg, col t = tw+l15 ----
    f32x4 aS  = {0.f, 0.f, 0.f, 0.f};
    f32x4 aM  = {0.f, 0.f, 0.f, 0.f};
    f32x4 aL0 = {0.f, 0.f, 0.f, 0.f};
    f32x4 aL1 = {0.f, 0.f, 0.f, 0.f};

    #pragma unroll
    for (int kp = 0; kp < 3; ++kp)
        #pragma unroll
        for (int q = 0; q < 2; ++q) {
            const int row = 30 + tw + l15 + kp;
            const f16x8 bh = *(const f16x8*)(&lds[row * 72 + q * 32 + lg * 8]);
            const f16x8 bv = *(const f16x8*)(&lds[6912 + row * 72 + q * 32 + lg * 8]);
            MFMA3(aS, pk + (2 * kp + q) * 1024 + la8, bh, bv);
        }
    #pragma unroll
    for (int kp = 0; kp < 5; ++kp)
        #pragma unroll
        for (int q = 0; q < 2; ++q) {
            const int row = 24 + tw + l15 + 2 * kp;
            const f16x8 bh = *(const f16x8*)(&lds[row * 72 + q * 32 + lg * 8]);
            const f16x8 bv = *(const f16x8*)(&lds[6912 + row * 72 + q * 32 + lg * 8]);
            MFMA3(aM, pk + (6 + 2 * kp + q) * 1024 + la8, bh, bv);
        }
    #pragma unroll 3
    for (int kp = 0; kp < 9; ++kp)
        #pragma unroll
        for (int q = 0; q < 2; ++q) {
            const int row = tw + l15 + 4 * kp;
            const f16x8 bh = *(const f16x8*)(&lds[row * 72 + q * 32 + lg * 8]);
            const f16x8 bv = *(const f16x8*)(&lds[6912 + row * 72 + q * 32 + lg * 8]);
            MFMA3(aL0, pk + (16 + 4 * kp + 2 * q) * 1024 + la8, bh, bv);
            MFMA3(aL1, pk + (16 + 4 * kp + 2 * q + 1) * 1024 + la8, bh, bv);
        }

    // ---- bias (+relu) + hi/lo stage into h planes [t][j], pitch 72 ----
#define STAGEH(ACC, BPTR, JB, RELU) do {                                   \
        const float4 bv_ = *(const float4*)(BPTR);                         \
        float x0_ = ACC[0] + bv_.x, x1_ = ACC[1] + bv_.y,                  \
              x2_ = ACC[2] + bv_.z, x3_ = ACC[3] + bv_.w;                  \
        if (RELU) { x0_ = fmaxf(x0_, 0.f); x1_ = fmaxf(x1_, 0.f);          \
                    x2_ = fmaxf(x2_, 0.f); x3_ = fmaxf(x3_, 0.f); }        \
        const f16 h0_ = (f16)x0_, h1_ = (f16)x1_;                          \
        const f16 h2_ = (f16)x2_, h3_ = (f16)x3_;                          \
        const int ro_ = (tw + l15) * 72 + (JB) + lg * 4;                   \
        *(f16x2*)(&lds[13824 + ro_])     = (f16x2){h0_, h1_};              \
        *(f16x2*)(&lds[13824 + ro_ + 2]) = (f16x2){h2_, h3_};              \
        *(f16x2*)(&lds[18432 + ro_])     =                                 \
            (f16x2){(f16)(x0_ - (float)h0_), (f16)(x1_ - (float)h1_)};     \
        *(f16x2*)(&lds[18432 + ro_ + 2]) =                                 \
            (f16x2){(f16)(x2_ - (float)h2_), (f16)(x3_ - (float)h3_)};     \
    } while (0)

    STAGEH(aS,  bs + lg * 4,       0,  true);
    STAGEH(aM,  bm + lg * 4,       16, true);
    STAGEH(aL0, bl + lg * 4,       32, true);
    STAGEH(aL1, bl + 16 + lg * 4,  48, true);
    // no barrier: each wave reads only its own 16 t rows below

    // ---- GEMM2: conv_out 64->64.  C[d][t] ----
    f32x4 o0 = {0.f, 0.f, 0.f, 0.f};
    f32x4 o1 = {0.f, 0.f, 0.f, 0.f};
    f32x4 o2 = {0.f, 0.f, 0.f, 0.f};
    f32x4 o3 = {0.f, 0.f, 0.f, 0.f};
    #pragma unroll
    for (int kh = 0; kh < 2; ++kh) {
        const f16x8 bh = *(const f16x8*)(&lds[13824 + (tw + l15) * 72 + kh * 32 + lg * 8]);
        const f16x8 bv = *(const f16x8*)(&lds[18432 + (tw + l15) * 72 + kh * 32 + lg * 8]);
        MFMA3(o0, pk + (52 + 0 + kh) * 1024 + la8, bh, bv);
        MFMA3(o1, pk + (52 + 2 + kh) * 1024 + la8, bh, bv);
        MFMA3(o2, pk + (52 + 4 + kh) * 1024 + la8, bh, bv);
        MFMA3(o3, pk + (52 + 6 + kh) * 1024 + la8, bh, bv);
    }

    if (!FINAL) {
        float* ob = out + (long)b * 64 * T_LEN + t0 + tw + l15;
        const float4 b0v = *(const float4*)(bo + lg * 4);
        const float4 b1v = *(const float4*)(bo + 16 + lg * 4);
        const float4 b2v = *(const float4*)(bo + 32 + lg * 4);
        const float4 b3v = *(const float4*)(bo + 48 + lg * 4);
#define STO4(ACC, BV, MS) do {                                             \
        ob[((MS) * 16 + lg * 4 + 0) * (long)T_LEN] = ACC[0] + BV.x;        \
        ob[((MS) * 16 + lg * 4 + 1) * (long)T_LEN] = ACC[1] + BV.y;        \
        ob[((MS) * 16 + lg * 4 + 2) * (long)T_LEN] = ACC[2] + BV.z;        \
        ob[((MS) * 16 + lg * 4 + 3) * (long)T_LEN] = ACC[3] + BV.w;        \
    } while (0)
        STO4(o0, b0v, 0);
        STO4(o1, b1v, 1);
        STO4(o2, b2v, 2);
        STO4(o3, b3v, 3);
#undef STO4
    } else {
        // ---- stage t2 (conv_out + bo, no relu) over h planes ----
        STAGEH(o0, bo + lg * 4,       0,  false);
        STAGEH(o1, bo + 16 + lg * 4,  16, false);
        STAGEH(o2, bo + 32 + lg * 4,  32, false);
        STAGEH(o3, bo + 48 + lg * 4,  48, false);

        // ---- GEMM3: dense 64->32.  C[e][t] ----
        f32x4 e0 = {0.f, 0.f, 0.f, 0.f};
        f32x4 e1 = {0.f, 0.f, 0.f, 0.f};
        #pragma unroll
        for (int kh = 0; kh < 2; ++kh) {
            const f16x8 bh = *(const f16x8*)(&lds[13824 + (tw + l15) * 72 + kh * 32 + lg * 8]);
            const f16x8 bv = *(const f16x8*)(&lds[18432 + (tw + l15) * 72 + kh * 32 + lg * 8]);
            MFMA3(e0, g_pk + (120 + 0 + kh) * 1024 + la8, bh, bv);
            MFMA3(e1, g_pk + (120 + 2 + kh) * 1024 + la8, bh, bv);
        }
        const float4 bd0 = *(const float4*)(bd + lg * 4);
        const float4 bd1 = *(const float4*)(bd + 16 + lg * 4);
        const float cI = 1.0f / (float)T_LEN;
        float u0 = tanhf(e0[0] + bd0.x) * cI;
        float u1 = tanhf(e0[1] + bd0.y) * cI;
        float u2 = tanhf(e0[2] + bd0.z) * cI;
        float u3 = tanhf(e0[3] + bd0.w) * cI;
        float u4 = tanhf(e1[0] + bd1.x) * cI;
        float u5 = tanhf(e1[1] + bd1.y) * cI;
        float u6 = tanhf(e1[2] + bd1.z) * cI;
        float u7 = tanhf(e1[3] + bd1.w) * cI;
#define RED(U) do { U += __shfl_xor(U, 1); U += __shfl_xor(U, 2);          \
                    U += __shfl_xor(U, 4); U += __shfl_xor(U, 8); } while (0)
        RED(u0); RED(u1); RED(u2); RED(u3);
        RED(u4); RED(u5); RED(u6); RED(u7);
#undef RED
        if (l15 == 0) {
            float* op = outp + b * 32;
            atomicAdd(op + lg * 4 + 0, u0);
            atomicAdd(op + lg * 4 + 1, u1);
            atomicAdd(op + lg * 4 + 2, u2);
            atomicAdd(op + lg * 4 + 3, u3);
            atomicAdd(op + 16 + lg * 4 + 0, u4);
            atomicAdd(op + 16 + lg * 4 + 1, u5);
            atomicAdd(op + 16 + lg * 4 + 2, u6);
            atomicAdd(op + 16 + lg * 4 + 3, u7);
        }
    }
#undef STAGEH
#undef MFMA3
}

extern "C" void kernel_launch(void* const* d_in, const int* in_sizes, int n_in,
                              void* d_out, int out_size, void* d_ws, size_t ws_size,
                              hipStream_t stream) {
    const float* x     = (const float*)d_in[0];
    const float* gcn_w = (const float*)d_in[1];
    const float* wd    = (const float*)d_in[2];
    const float* bd    = (const float*)d_in[3];
    const float* t1_ws = (const float*)d_in[4];
    const float* t1_bs = (const float*)d_in[5];
    const float* t1_wm = (const float*)d_in[6];
    const float* t1_bm = (const float*)d_in[7];
    const float* t1_wl = (const float*)d_in[8];
    const float* t1_bl = (const float*)d_in[9];
    const float* t1_wo = (const float*)d_in[10];
    const float* t1_bo = (const float*)d_in[11];
    const float* t2_ws = (const float*)d_in[12];
    const float* t2_bs = (const float*)d_in[13];
    const float* t2_wm = (const float*)d_in[14];
    const float* t2_bm = (const float*)d_in[15];
    const float* t2_wl = (const float*)d_in[16];
    const float* t2_bl = (const float*)d_in[17];
    const float* t2_wo = (const float*)d_in[18];
    const float* t2_bo = (const float*)d_in[19];

    float* b0 = (float*)d_ws;                          // [16][64][4096]
    float* b1 = b0 + (size_t)BATCH * 64 * T_LEN;       // [16][64][4096]

    hipMemsetAsync(d_out, 0, (size_t)out_size * sizeof(float), stream);

    k_pack<<<dim3(124), 256, 0, stream>>>(
        t1_ws, t1_wm, t1_wl, t1_wo, t2_ws, t2_wm, t2_wl, t2_wo, wd);

    k_gcn<<<dim3(T_LEN / 32, BATCH), 256, 0, stream>>>(x, gcn_w, b0);

    k_mstcn<false><<<dim3(T_LEN / 64, BATCH), 256, 0, stream>>>(
        b0, t1_bs, t1_bm, t1_bl, t1_bo, 0,
        b1, nullptr, nullptr);

    k_mstcn<true><<<dim3(T_LEN / 64, BATCH), 256, 0, stream>>>(
        b1, t2_bs, t2_bm, t2_bl, t2_bo, 61440,
        nullptr, bd, (float*)d_out);
}

// Round 6
// 253.742 us; speedup vs baseline: 2.5811x; 1.0912x over previous
//
#include <hip/hip_runtime.h>
#include <hip/hip_bf16.h>
#include <math.h>

#define T_LEN 4096
#define BATCH 16

typedef _Float16 f16;
typedef _Float16 f16x2 __attribute__((ext_vector_type(2)));
typedef _Float16 f16x8 __attribute__((ext_vector_type(8)));
typedef float f32x4 __attribute__((ext_vector_type(4)));

// Packed MFMA A-fragments, hi/lo split-f16. 132 logical frags:
// per layer (60): S[k(3)][q(2)]=0..5, M[k(5)][q(2)]=6..15,
// L[k(9)][q(2)][ms(2)]=16..51, O[ms(4)][kh(2)]=52..59; layer stride 60.
// D (dense 64->32): 120..123 = [ms(2)][kh(2)].
// GCN: 124..127 = bone proj A[df] (K rows 0..9 = gcn_w, rest 0);
//      128..131 = palm proj A[df] (K rows 0..17 = gcn_w, rest 0).
// Frag f: hi at f*1024 + lane*8, lo at f*1024 + 512 + lane*8 (f16 units).
// A[m][k]: m = lane&15, k = (lane>>4)*8 + j  (16x16x32 f16 A-layout).
__device__ __align__(16) f16 g_pk[132 * 1024];

// ---------------------------------------------------------------------------
// k_pack: one-time weight repack -> MFMA fragments (hi/lo f16).
// ---------------------------------------------------------------------------
__global__ void k_pack(
    const float* __restrict__ ws1, const float* __restrict__ wm1,
    const float* __restrict__ wl1, const float* __restrict__ wo1,
    const float* __restrict__ ws2, const float* __restrict__ wm2,
    const float* __restrict__ wl2, const float* __restrict__ wo2,
    const float* __restrict__ wd,  const float* __restrict__ gcn_w)
{
    const int g = blockIdx.x;          // 0..131 logical frag
    const int tid = threadIdx.x;
    #pragma unroll
    for (int u = 0; u < 2; ++u) {
        const int e = tid * 2 + u;     // 0..511
        const int lane = e >> 3, j = e & 7;
        const int m = lane & 15, k = (lane >> 4) * 8 + j;
        float w;
        if (g < 120) {
            const int layer = g / 60, r0 = g % 60;
            const float* pws = layer ? ws2 : ws1;
            const float* pwm = layer ? wm2 : wm1;
            const float* pwl = layer ? wl2 : wl1;
            const float* pwo = layer ? wo2 : wo1;
            if (r0 < 6) {
                const int kp = r0 >> 1, q = r0 & 1;
                w = pws[(kp * 64 + q * 32 + k) * 16 + m];        // ws[k][c][j]
            } else if (r0 < 16) {
                const int r = r0 - 6, kp = r >> 1, q = r & 1;
                w = pwm[(kp * 64 + q * 32 + k) * 16 + m];
            } else if (r0 < 52) {
                const int r = r0 - 16, kp = r >> 2, q = (r >> 1) & 1, ms = r & 1;
                w = pwl[(kp * 64 + q * 32 + k) * 32 + ms * 16 + m];
            } else {
                const int r = r0 - 52, ms = r >> 1, kh = r & 1;
                w = pwo[(kh * 32 + k) * 64 + ms * 16 + m];       // wo[j][d] -> A[d][j]
            }
        } else if (g < 124) {
            const int r = g - 120, ms = r >> 1, kh = r & 1;
            w = wd[(kh * 32 + k) * 32 + ms * 16 + m];            // wd[d][e] -> A[e][d]
        } else {
            const int r = g - 124, df = r & 3;
            const int lim = (r >> 2) ? 18 : 10;                  // palm : bone
            w = (k < lim) ? gcn_w[k * 64 + df * 16 + m] : 0.f;
        }
        const f16 hi = (f16)w;
        const f16 lo = (f16)(w - (float)hi);
        g_pk[g * 1024 + e] = hi;
        g_pk[g * 1024 + 512 + e] = lo;
    }
}

__device__ inline f32x4 mfma3z(f16x8 ah, f16x8 al, f16x8 bh, f16x8 bl) {
    f32x4 a = {0.f, 0.f, 0.f, 0.f};
    a = __builtin_amdgcn_mfma_f32_16x16x32_f16(ah, bh, a, 0, 0, 0);
    a = __builtin_amdgcn_mfma_f32_16x16x32_f16(ah, bl, a, 0, 0, 0);
    a = __builtin_amdgcn_mfma_f32_16x16x32_f16(al, bh, a, 0, 0, 0);
    return a;
}

// ---------------------------------------------------------------------------
// k_gcn R14: MFMA rewrite (same split-f16 scheme as R13's k_mstcn).
// R13 post-mortem: k_gcn is now the top kernel (76us) with the familiar
// VALU-convoy signature (MfmaUtil 0, VALUBusy 40%, 1.3M bank conflicts).
// Structure exploited: all 20 bones share gcn_w[0:10] -> ONE register-held
// A-frag set (8 frags), zero weight streaming (the single-stage GEMM
// formulation would stream 352KB/wave of A -> L2-bound; this streams 0).
// Per bone: B-frag built from global x (channels used exactly once ->
// no LDS staging at all; bank conflicts gone by construction), 12 MFMAs
// (16x16x32 only - layouts proven by R13), then R8's per-lane
// star/s12/hprev propagation chain on the C-frags (cols=t, rows=d ->
// node mixing is register-local). Pad K-lanes read safe in-bounds finite
// x (max ch 217 checked) and are killed by zeros in A.
// ---------------------------------------------------------------------------
__global__ __launch_bounds__(256) void k_gcn(
    const float* __restrict__ x,      // [B][T][218]
    float* __restrict__ hp)           // [B][64][T]
{
    const int b   = blockIdx.y;
    const int t0  = blockIdx.x * 64;
    const int tid = threadIdx.x;
    const int lane = tid & 63, wid = tid >> 6;
    const int l15 = lane & 15, lg = lane >> 4;
    const int t = t0 + wid * 16 + l15;
    const float* xrow = x + ((long)b * T_LEN + t) * 218;
    const int la8 = lane * 8;

    const float cP = 1.0f / 6.0f;
    const float cS = 0.23570226039551584f;   // 1/sqrt(18)
    const float c3 = 1.0f / 3.0f;
    const float cT = 0.4082482904638631f;    // 1/sqrt(6)
    const float cH = 0.5f;

    // ---- palm: h0 = x[0:18] . gcn_w  (K-pad lanes read ch16..23, A=0) ----
    f32x4 h0[4];
    {
        float vv[8];
        const int po = (lg < 2) ? lg * 8 : 16;
        *(float2*)(vv + 0) = *(const float2*)(xrow + po);
        *(float2*)(vv + 2) = *(const float2*)(xrow + po + 2);
        *(float2*)(vv + 4) = *(const float2*)(xrow + po + 4);
        *(float2*)(vv + 6) = *(const float2*)(xrow + po + 6);
        f16x8 bh, bl;
        #pragma unroll
        for (int j = 0; j < 8; ++j) {
            const f16 h = (f16)vv[j];
            bh[j] = h; bl[j] = (f16)(vv[j] - (float)h);
        }
        #pragma unroll
        for (int df = 0; df < 4; ++df) {
            const f16x8 ah = *(const f16x8*)(g_pk + (128 + df) * 1024 + la8);
            const f16x8 al = *(const f16x8*)(g_pk + (128 + df) * 1024 + 512 + la8);
            h0[df] = mfma3z(ah, al, bh, bl);
        }
    }

    // ---- bone projection A-frags: register-resident, shared by all 20 ----
    f16x8 Abh[4], Abl[4];
    #pragma unroll
    for (int df = 0; df < 4; ++df) {
        Abh[df] = *(const f16x8*)(g_pk + (124 + df) * 1024 + la8);
        Abl[df] = *(const f16x8*)(g_pk + (124 + df) * 1024 + 512 + la8);
    }

    f32x4 pool[4], star[4], s12[4], hprev[4];
    #pragma unroll
    for (int df = 0; df < 4; ++df) {
        pool[df] = (f32x4){0.f, 0.f, 0.f, 0.f};
        star[df] = (f32x4){0.f, 0.f, 0.f, 0.f};
    }

    #pragma unroll 1
    for (int f = 0; f < 5; ++f) {
        #pragma unroll
        for (int n = 0; n < 4; ++n) {
            const int w = 4 * f + n;
            const float* bp = xrow + 18 + 10 * w;
            // lg0: ch0..7; lg1: ch8,9 (+finite dup); lg2/3: finite dup, A=0
            float vv[8];
            const bool g0 = (lg == 0);
            *(float2*)(vv + 0) = *(const float2*)(bp + ((lg == 1) ? 8 : 0));
            *(float2*)(vv + 2) = *(const float2*)(bp + (g0 ? 2 : 0));
            *(float2*)(vv + 4) = *(const float2*)(bp + (g0 ? 4 : 0));
            *(float2*)(vv + 6) = *(const float2*)(bp + (g0 ? 6 : 0));
            f16x8 bh, bl;
            #pragma unroll
            for (int j = 0; j < 8; ++j) {
                const f16 h = (f16)vv[j];
                bh[j] = h; bl[j] = (f16)(vv[j] - (float)h);
            }
            f32x4 hn[4];
            #pragma unroll
            for (int df = 0; df < 4; ++df)
                hn[df] = mfma3z(Abh[df], Abl[df], bh, bl);

            #pragma unroll
            for (int df = 0; df < 4; ++df)
                #pragma unroll
                for (int i = 0; i < 4; ++i) {
                    const float h = hn[df][i];
                    if (n == 0) {
                        star[df][i] += h;
                        s12[df][i] = h;
                        hprev[df][i] = h;
                    } else if (n == 1) {
                        const float pa = fmaf(cS, h0[df][i], c3 * (s12[df][i] + h));
                        pool[df][i] += fmaxf(pa, 0.f);
                        s12[df][i] += h;
                        hprev[df][i] = h;
                    } else if (n == 2) {
                        const float pb = c3 * (s12[df][i] + h);
                        pool[df][i] += fmaxf(pb, 0.f);
                        s12[df][i] = hprev[df][i] + h;
                        hprev[df][i] = h;
                    } else {
                        const float pc = fmaf(cT, h, c3 * s12[df][i]);
                        const float pe = fmaf(cT, hprev[df][i], cH * h);
                        pool[df][i] += fmaxf(pc, 0.f) + fmaxf(pe, 0.f);
                    }
                }
        }
    }

    float* hpb = hp + (long)b * 64 * T_LEN + t;
    #pragma unroll
    for (int df = 0; df < 4; ++df)
        #pragma unroll
        for (int i = 0; i < 4; ++i) {
            const float p0 = fmaf(cP, h0[df][i], cS * star[df][i]);
            hpb[(long)(df * 16 + lg * 4 + i) * T_LEN] =
                (pool[df][i] + fmaxf(p0, 0.f)) * (1.0f / 21.0f);
        }
}

// ---------------------------------------------------------------------------
// k_mstcn R13: MFMA rewrite (split-f16 hi/lo, 3 mfma per logical product).
// (unchanged from R13 - passed at ~70us/dispatch)
// ---------------------------------------------------------------------------
template <bool FINAL>
__global__ __launch_bounds__(256, 3) void k_mstcn(
    const float* __restrict__ in,   // [B][64][T]
    const float* __restrict__ bs, const float* __restrict__ bm,
    const float* __restrict__ bl, const float* __restrict__ bo,
    int pkoff,                      // layer * 61440 (f16 units)
    float* __restrict__ out,        // [B][64][T]  (FINAL=false)
    const float* __restrict__ bd,   // [32]        (FINAL=true)
    float* __restrict__ outp)       // [B][32]     (FINAL=true)
{
    // f16 units: XH=0(96x72), XL=6912, HH=13824(64x72), HL=18432; total 23040
    __shared__ __align__(16) f16 lds[23040];

    const int b   = blockIdx.y;
    const int t0  = blockIdx.x * 64;
    const int tid = threadIdx.x;
    const float* inb = in + (long)b * 64 * T_LEN;

    // ---- stage x window [t0-32, t0+64) -> transposed hi/lo planes ----
    {
        const int c0 = (tid >> 3) * 2;      // c pair
        const int tq = (tid & 7) * 12;      // 12 t per thread
        float v0[12], v1[12];
        if (t0 != 0 || tq >= 32) {
            const float* r0 = inb + (long)c0 * T_LEN + (t0 - 32 + tq);
            const float* r1 = r0 + T_LEN;
            #pragma unroll
            for (int mq = 0; mq < 3; ++mq) {
                *(float4*)(v0 + 4 * mq) = *(const float4*)(r0 + 4 * mq);
                *(float4*)(v1 + 4 * mq) = *(const float4*)(r1 + 4 * mq);
            }
        } else {
            #pragma unroll
            for (int i = 0; i < 12; ++i) {
                const int tg = tq + i - 32;
                v0[i] = (tg >= 0) ? inb[(long)c0 * T_LEN + tg] : 0.f;
                v1[i] = (tg >= 0) ? inb[(long)(c0 + 1) * T_LEN + tg] : 0.f;
            }
        }
        #pragma unroll
        for (int i = 0; i < 12; ++i) {
            const f16 h0 = (f16)v0[i], h1 = (f16)v1[i];
            const f16 l0 = (f16)(v0[i] - (float)h0), l1 = (f16)(v1[i] - (float)h1);
            const int row = tq + i;
            *(f16x2*)(&lds[row * 72 + c0])        = (f16x2){h0, h1};
            *(f16x2*)(&lds[6912 + row * 72 + c0]) = (f16x2){l0, l1};
        }
    }
    __syncthreads();

    const int lane = tid & 63, wid = tid >> 6;
    const int l15 = lane & 15, lg = lane >> 4;
    const int tw  = wid * 16;
    const f16* pk = g_pk + pkoff;
    const int la8 = lane * 8;

#define MFMA3(ACC, PA, BH, BL) do {                                        \
        const f16x8 ah_ = *(const f16x8*)(PA);                             \
        const f16x8 al_ = *(const f16x8*)((PA) + 512);                     \
        ACC = __builtin_amdgcn_mfma_f32_16x16x32_f16(ah_, BH, ACC, 0,0,0); \
        ACC = __builtin_amdgcn_mfma_f32_16x16x32_f16(ah_, BL, ACC, 0,0,0); \
        ACC = __builtin_amdgcn_mfma_f32_16x16x32_f16(al_, BH, ACC, 0,0,0); \
    } while (0)

    // ---- GEMM1: branches.  C[j][t]: row j = lg*4+reg, col t = tw+l15 ----
    f32x4 aS  = {0.f, 0.f, 0.f, 0.f};
    f32x4 aM  = {0.f, 0.f, 0.f, 0.f};
    f32x4 aL0 = {0.f, 0.f, 0.f, 0.f};
    f32x4 aL1 = {0.f, 0.f, 0.f, 0.f};

    #pragma unroll
    for (int kp = 0; kp < 3; ++kp)
        #pragma unroll
        for (int q = 0; q < 2; ++q) {
            const int row = 30 + tw + l15 + kp;
            const f16x8 bh = *(const f16x8*)(&lds[row * 72 + q * 32 + lg * 8]);
            const f16x8 bv = *(const f16x8*)(&lds[6912 + row * 72 + q * 32 + lg * 8]);
            MFMA3(aS, pk + (2 * kp + q) * 1024 + la8, bh, bv);
        }
    #pragma unroll
    for (int kp = 0; kp < 5; ++kp)
        #pragma unroll
        for (int q = 0; q < 2; ++q) {
            const int row = 24 + tw + l15 + 2 * kp;
            const f16x8 bh = *(const f16x8*)(&lds[row * 72 + q * 32 + lg * 8]);
            const f16x8 bv = *(const f16x8*)(&lds[6912 + row * 72 + q * 32 + lg * 8]);
            MFMA3(aM, pk + (6 + 2 * kp + q) * 1024 + la8, bh, bv);
        }
    #pragma unroll 3
    for (int kp = 0; kp < 9; ++kp)
        #pragma unroll
        for (int q = 0; q < 2; ++q) {
            const int row = tw + l15 + 4 * kp;
            const f16x8 bh = *(const f16x8*)(&lds[row * 72 + q * 32 + lg * 8]);
            const f16x8 bv = *(const f16x8*)(&lds[6912 + row * 72 + q * 32 + lg * 8]);
            MFMA3(aL0, pk + (16 + 4 * kp + 2 * q) * 1024 + la8, bh, bv);
            MFMA3(aL1, pk + (16 + 4 * kp + 2 * q + 1) * 1024 + la8, bh, bv);
        }

    // ---- bias (+relu) + hi/lo stage into h planes [t][j], pitch 72 ----
#define STAGEH(ACC, BPTR, JB, RELU) do {                                   \
        const float4 bv_ = *(const float4*)(BPTR);                         \
        float x0_ = ACC[0] + bv_.x, x1_ = ACC[1] + bv_.y,                  \
              x2_ = ACC[2] + bv_.z, x3_ = ACC[3] + bv_.w;                  \
        if (RELU) { x0_ = fmaxf(x0_, 0.f); x1_ = fmaxf(x1_, 0.f);          \
                    x2_ = fmaxf(x2_, 0.f); x3_ = fmaxf(x3_, 0.f); }        \
        const f16 h0_ = (f16)x0_, h1_ = (f16)x1_;                          \
        const f16 h2_ = (f16)x2_, h3_ = (f16)x3_;                          \
        const int ro_ = (tw + l15) * 72 + (JB) + lg * 4;                   \
        *(f16x2*)(&lds[13824 + ro_])     = (f16x2){h0_, h1_};              \
        *(f16x2*)(&lds[13824 + ro_ + 2]) = (f16x2){h2_, h3_};              \
        *(f16x2*)(&lds[18432 + ro_])     =                                 \
            (f16x2){(f16)(x0_ - (float)h0_), (f16)(x1_ - (float)h1_)};     \
        *(f16x2*)(&lds[18432 + ro_ + 2]) =                                 \
            (f16x2){(f16)(x2_ - (float)h2_), (f16)(x3_ - (float)h3_)};     \
    } while (0)

    STAGEH(aS,  bs + lg * 4,       0,  true);
    STAGEH(aM,  bm + lg * 4,       16, true);
    STAGEH(aL0, bl + lg * 4,       32, true);
    STAGEH(aL1, bl + 16 + lg * 4,  48, true);
    // no barrier: each wave reads only its own 16 t rows below

    // ---- GEMM2: conv_out 64->64.  C[d][t] ----
    f32x4 o0 = {0.f, 0.f, 0.f, 0.f};
    f32x4 o1 = {0.f, 0.f, 0.f, 0.f};
    f32x4 o2 = {0.f, 0.f, 0.f, 0.f};
    f32x4 o3 = {0.f, 0.f, 0.f, 0.f};
    #pragma unroll
    for (int kh = 0; kh < 2; ++kh) {
        const f16x8 bh = *(const f16x8*)(&lds[13824 + (tw + l15) * 72 + kh * 32 + lg * 8]);
        const f16x8 bv = *(const f16x8*)(&lds[18432 + (tw + l15) * 72 + kh * 32 + lg * 8]);
        MFMA3(o0, pk + (52 + 0 + kh) * 1024 + la8, bh, bv);
        MFMA3(o1, pk + (52 + 2 + kh) * 1024 + la8, bh, bv);
        MFMA3(o2, pk + (52 + 4 + kh) * 1024 + la8, bh, bv);
        MFMA3(o3, pk + (52 + 6 + kh) * 1024 + la8, bh, bv);
    }

    if (!FINAL) {
        float* ob = out + (long)b * 64 * T_LEN + t0 + tw + l15;
        const float4 b0v = *(const float4*)(bo + lg * 4);
        const float4 b1v = *(const float4*)(bo + 16 + lg * 4);
        const float4 b2v = *(const float4*)(bo + 32 + lg * 4);
        const float4 b3v = *(const float4*)(bo + 48 + lg * 4);
#define STO4(ACC, BV, MS) do {                                             \
        ob[((MS) * 16 + lg * 4 + 0) * (long)T_LEN] = ACC[0] + BV.x;        \
        ob[((MS) * 16 + lg * 4 + 1) * (long)T_LEN] = ACC[1] + BV.y;        \
        ob[((MS) * 16 + lg * 4 + 2) * (long)T_LEN] = ACC[2] + BV.z;        \
        ob[((MS) * 16 + lg * 4 + 3) * (long)T_LEN] = ACC[3] + BV.w;        \
    } while (0)
        STO4(o0, b0v, 0);
        STO4(o1, b1v, 1);
        STO4(o2, b2v, 2);
        STO4(o3, b3v, 3);
#undef STO4
    } else {
        // ---- stage t2 (conv_out + bo, no relu) over h planes ----
        STAGEH(o0, bo + lg * 4,       0,  false);
        STAGEH(o1, bo + 16 + lg * 4,  16, false);
        STAGEH(o2, bo + 32 + lg * 4,  32, false);
        STAGEH(o3, bo + 48 + lg * 4,  48, false);

        // ---- GEMM3: dense 64->32.  C[e][t] ----
        f32x4 e0 = {0.f, 0.f, 0.f, 0.f};
        f32x4 e1 = {0.f, 0.f, 0.f, 0.f};
        #pragma unroll
        for (int kh = 0; kh < 2; ++kh) {
            const f16x8 bh = *(const f16x8*)(&lds[13824 + (tw + l15) * 72 + kh * 32 + lg * 8]);
            const f16x8 bv = *(const f16x8*)(&lds[18432 + (tw + l15) * 72 + kh * 32 + lg * 8]);
            MFMA3(e0, g_pk + (120 + 0 + kh) * 1024 + la8, bh, bv);
            MFMA3(e1, g_pk + (120 + 2 + kh) * 1024 + la8, bh, bv);
        }
        const float4 bd0 = *(const float4*)(bd + lg * 4);
        const float4 bd1 = *(const float4*)(bd + 16 + lg * 4);
        const float cI = 1.0f / (float)T_LEN;
        float u0 = tanhf(e0[0] + bd0.x) * cI;
        float u1 = tanhf(e0[1] + bd0.y) * cI;
        float u2 = tanhf(e0[2] + bd0.z) * cI;
        float u3 = tanhf(e0[3] + bd0.w) * cI;
        float u4 = tanhf(e1[0] + bd1.x) * cI;
        float u5 = tanhf(e1[1] + bd1.y) * cI;
        float u6 = tanhf(e1[2] + bd1.z) * cI;
        float u7 = tanhf(e1[3] + bd1.w) * cI;
#define RED(U) do { U += __shfl_xor(U, 1); U += __shfl_xor(U, 2);          \
                    U += __shfl_xor(U, 4); U += __shfl_xor(U, 8); } while (0)
        RED(u0); RED(u1); RED(u2); RED(u3);
        RED(u4); RED(u5); RED(u6); RED(u7);
#undef RED
        if (l15 == 0) {
            float* op = outp + b * 32;
            atomicAdd(op + lg * 4 + 0, u0);
            atomicAdd(op + lg * 4 + 1, u1);
            atomicAdd(op + lg * 4 + 2, u2);
            atomicAdd(op + lg * 4 + 3, u3);
            atomicAdd(op + 16 + lg * 4 + 0, u4);
            atomicAdd(op + 16 + lg * 4 + 1, u5);
            atomicAdd(op + 16 + lg * 4 + 2, u6);
            atomicAdd(op + 16 + lg * 4 + 3, u7);
        }
    }
#undef STAGEH
#undef MFMA3
}

extern "C" void kernel_launch(void* const* d_in, const int* in_sizes, int n_in,
                              void* d_out, int out_size, void* d_ws, size_t ws_size,
                              hipStream_t stream) {
    const float* x     = (const float*)d_in[0];
    const float* gcn_w = (const float*)d_in[1];
    const float* wd    = (const float*)d_in[2];
    const float* bd    = (const float*)d_in[3];
    const float* t1_ws = (const float*)d_in[4];
    const float* t1_bs = (const float*)d_in[5];
    const float* t1_wm = (const float*)d_in[6];
    const float* t1_bm = (const float*)d_in[7];
    const float* t1_wl = (const float*)d_in[8];
    const float* t1_bl = (const float*)d_in[9];
    const float* t1_wo = (const float*)d_in[10];
    const float* t1_bo = (const float*)d_in[11];
    const float* t2_ws = (const float*)d_in[12];
    const float* t2_bs = (const float*)d_in[13];
    const float* t2_wm = (const float*)d_in[14];
    const float* t2_bm = (const float*)d_in[15];
    const float* t2_wl = (const float*)d_in[16];
    const float* t2_bl = (const float*)d_in[17];
    const float* t2_wo = (const float*)d_in[18];
    const float* t2_bo = (const float*)d_in[19];

    float* b0 = (float*)d_ws;                          // [16][64][4096]
    float* b1 = b0 + (size_t)BATCH * 64 * T_LEN;       // [16][64][4096]

    hipMemsetAsync(d_out, 0, (size_t)out_size * sizeof(float), stream);

    k_pack<<<dim3(132), 256, 0, stream>>>(
        t1_ws, t1_wm, t1_wl, t1_wo, t2_ws, t2_wm, t2_wl, t2_wo, wd, gcn_w);

    k_gcn<<<dim3(T_LEN / 64, BATCH), 256, 0, stream>>>(x, b0);

    k_mstcn<false><<<dim3(T_LEN / 64, BATCH), 256, 0, stream>>>(
        b0, t1_bs, t1_bm, t1_bl, t1_bo, 0,
        b1, nullptr, nullptr);

    k_mstcn<true><<<dim3(T_LEN / 64, BATCH), 256, 0, stream>>>(
        b1, t2_bs, t2_bm, t2_bl, t2_bo, 61440,
        nullptr, bd, (float*)d_out);
}

// Round 7
// 239.612 us; speedup vs baseline: 2.7333x; 1.0590x over previous
//
#include <hip/hip_runtime.h>
#include <hip/hip_bf16.h>
#include <math.h>

#define T_LEN 4096
#define BATCH 16

typedef _Float16 f16;
typedef _Float16 f16x2 __attribute__((ext_vector_type(2)));
typedef _Float16 f16x8 __attribute__((ext_vector_type(8)));
typedef float f32x4 __attribute__((ext_vector_type(4)));

// Packed MFMA A-fragments, hi/lo split-f16. 132 logical frags:
// per layer (60): S[k(3)][q(2)]=0..5, M[k(5)][q(2)]=6..15,
// L[k(9)][q(2)][ms(2)]=16..51, O[ms(4)][kh(2)]=52..59; layer stride 60.
// D (dense 64->32): 120..123 = [ms(2)][kh(2)].
// GCN: 124..127 = bone proj A[df]; 128..131 = palm proj A[df].
// Frag f: hi at f*1024 + lane*8, lo at f*1024 + 512 + lane*8 (f16 units).
// A[m][k]: m = lane&15, k = (lane>>4)*8 + j  (16x16x32 f16 A-layout).
__device__ __align__(16) f16 g_pk[132 * 1024];

// ---------------------------------------------------------------------------
// k_pack: one-time weight repack -> MFMA fragments (hi/lo f16).
// ---------------------------------------------------------------------------
__global__ void k_pack(
    const float* __restrict__ ws1, const float* __restrict__ wm1,
    const float* __restrict__ wl1, const float* __restrict__ wo1,
    const float* __restrict__ ws2, const float* __restrict__ wm2,
    const float* __restrict__ wl2, const float* __restrict__ wo2,
    const float* __restrict__ wd,  const float* __restrict__ gcn_w)
{
    const int g = blockIdx.x;          // 0..131 logical frag
    const int tid = threadIdx.x;
    #pragma unroll
    for (int u = 0; u < 2; ++u) {
        const int e = tid * 2 + u;     // 0..511
        const int lane = e >> 3, j = e & 7;
        const int m = lane & 15, k = (lane >> 4) * 8 + j;
        float w;
        if (g < 120) {
            const int layer = g / 60, r0 = g % 60;
            const float* pws = layer ? ws2 : ws1;
            const float* pwm = layer ? wm2 : wm1;
            const float* pwl = layer ? wl2 : wl1;
            const float* pwo = layer ? wo2 : wo1;
            if (r0 < 6) {
                const int kp = r0 >> 1, q = r0 & 1;
                w = pws[(kp * 64 + q * 32 + k) * 16 + m];        // ws[k][c][j]
            } else if (r0 < 16) {
                const int r = r0 - 6, kp = r >> 1, q = r & 1;
                w = pwm[(kp * 64 + q * 32 + k) * 16 + m];
            } else if (r0 < 52) {
                const int r = r0 - 16, kp = r >> 2, q = (r >> 1) & 1, ms = r & 1;
                w = pwl[(kp * 64 + q * 32 + k) * 32 + ms * 16 + m];
            } else {
                const int r = r0 - 52, ms = r >> 1, kh = r & 1;
                w = pwo[(kh * 32 + k) * 64 + ms * 16 + m];       // wo[j][d] -> A[d][j]
            }
        } else if (g < 124) {
            const int r = g - 120, ms = r >> 1, kh = r & 1;
            w = wd[(kh * 32 + k) * 32 + ms * 16 + m];            // wd[d][e] -> A[e][d]
        } else {
            const int r = g - 124, df = r & 3;
            const int lim = (r >> 2) ? 18 : 10;                  // palm : bone
            w = (k < lim) ? gcn_w[k * 64 + df * 16 + m] : 0.f;
        }
        const f16 hi = (f16)w;
        const f16 lo = (f16)(w - (float)hi);
        g_pk[g * 1024 + e] = hi;
        g_pk[g * 1024 + 512 + e] = lo;
    }
}

__device__ inline f32x4 mfma3z(f16x8 ah, f16x8 al, f16x8 bh, f16x8 bl) {
    f32x4 a = {0.f, 0.f, 0.f, 0.f};
    a = __builtin_amdgcn_mfma_f32_16x16x32_f16(ah, bh, a, 0, 0, 0);
    a = __builtin_amdgcn_mfma_f32_16x16x32_f16(ah, bl, a, 0, 0, 0);
    a = __builtin_amdgcn_mfma_f32_16x16x32_f16(al, bh, a, 0, 0, 0);
    return a;
}

// ---------------------------------------------------------------------------
// k_gcn R14: MFMA rewrite. (unchanged - no longer in top-5)
// ---------------------------------------------------------------------------
__global__ __launch_bounds__(256) void k_gcn(
    const float* __restrict__ x,      // [B][T][218]
    float* __restrict__ hp)           // [B][64][T]
{
    const int b   = blockIdx.y;
    const int t0  = blockIdx.x * 64;
    const int tid = threadIdx.x;
    const int lane = tid & 63, wid = tid >> 6;
    const int l15 = lane & 15, lg = lane >> 4;
    const int t = t0 + wid * 16 + l15;
    const float* xrow = x + ((long)b * T_LEN + t) * 218;
    const int la8 = lane * 8;

    const float cP = 1.0f / 6.0f;
    const float cS = 0.23570226039551584f;   // 1/sqrt(18)
    const float c3 = 1.0f / 3.0f;
    const float cT = 0.4082482904638631f;    // 1/sqrt(6)
    const float cH = 0.5f;

    // ---- palm: h0 = x[0:18] . gcn_w  (K-pad lanes read ch16..23, A=0) ----
    f32x4 h0[4];
    {
        float vv[8];
        const int po = (lg < 2) ? lg * 8 : 16;
        *(float2*)(vv + 0) = *(const float2*)(xrow + po);
        *(float2*)(vv + 2) = *(const float2*)(xrow + po + 2);
        *(float2*)(vv + 4) = *(const float2*)(xrow + po + 4);
        *(float2*)(vv + 6) = *(const float2*)(xrow + po + 6);
        f16x8 bh, bl;
        #pragma unroll
        for (int j = 0; j < 8; ++j) {
            const f16 h = (f16)vv[j];
            bh[j] = h; bl[j] = (f16)(vv[j] - (float)h);
        }
        #pragma unroll
        for (int df = 0; df < 4; ++df) {
            const f16x8 ah = *(const f16x8*)(g_pk + (128 + df) * 1024 + la8);
            const f16x8 al = *(const f16x8*)(g_pk + (128 + df) * 1024 + 512 + la8);
            h0[df] = mfma3z(ah, al, bh, bl);
        }
    }

    // ---- bone projection A-frags: register-resident, shared by all 20 ----
    f16x8 Abh[4], Abl[4];
    #pragma unroll
    for (int df = 0; df < 4; ++df) {
        Abh[df] = *(const f16x8*)(g_pk + (124 + df) * 1024 + la8);
        Abl[df] = *(const f16x8*)(g_pk + (124 + df) * 1024 + 512 + la8);
    }

    f32x4 pool[4], star[4], s12[4], hprev[4];
    #pragma unroll
    for (int df = 0; df < 4; ++df) {
        pool[df] = (f32x4){0.f, 0.f, 0.f, 0.f};
        star[df] = (f32x4){0.f, 0.f, 0.f, 0.f};
    }

    #pragma unroll 1
    for (int f = 0; f < 5; ++f) {
        #pragma unroll
        for (int n = 0; n < 4; ++n) {
            const int w = 4 * f + n;
            const float* bp = xrow + 18 + 10 * w;
            float vv[8];
            const bool g0 = (lg == 0);
            *(float2*)(vv + 0) = *(const float2*)(bp + ((lg == 1) ? 8 : 0));
            *(float2*)(vv + 2) = *(const float2*)(bp + (g0 ? 2 : 0));
            *(float2*)(vv + 4) = *(const float2*)(bp + (g0 ? 4 : 0));
            *(float2*)(vv + 6) = *(const float2*)(bp + (g0 ? 6 : 0));
            f16x8 bh, bl;
            #pragma unroll
            for (int j = 0; j < 8; ++j) {
                const f16 h = (f16)vv[j];
                bh[j] = h; bl[j] = (f16)(vv[j] - (float)h);
            }
            f32x4 hn[4];
            #pragma unroll
            for (int df = 0; df < 4; ++df)
                hn[df] = mfma3z(Abh[df], Abl[df], bh, bl);

            #pragma unroll
            for (int df = 0; df < 4; ++df)
                #pragma unroll
                for (int i = 0; i < 4; ++i) {
                    const float h = hn[df][i];
                    if (n == 0) {
                        star[df][i] += h;
                        s12[df][i] = h;
                        hprev[df][i] = h;
                    } else if (n == 1) {
                        const float pa = fmaf(cS, h0[df][i], c3 * (s12[df][i] + h));
                        pool[df][i] += fmaxf(pa, 0.f);
                        s12[df][i] += h;
                        hprev[df][i] = h;
                    } else if (n == 2) {
                        const float pb = c3 * (s12[df][i] + h);
                        pool[df][i] += fmaxf(pb, 0.f);
                        s12[df][i] = hprev[df][i] + h;
                        hprev[df][i] = h;
                    } else {
                        const float pc = fmaf(cT, h, c3 * s12[df][i]);
                        const float pe = fmaf(cT, hprev[df][i], cH * h);
                        pool[df][i] += fmaxf(pc, 0.f) + fmaxf(pe, 0.f);
                    }
                }
        }
    }

    float* hpb = hp + (long)b * 64 * T_LEN + t;
    #pragma unroll
    for (int df = 0; df < 4; ++df)
        #pragma unroll
        for (int i = 0; i < 4; ++i) {
            const float p0 = fmaf(cP, h0[df][i], cS * star[df][i]);
            hpb[(long)(df * 16 + lg * 4 + i) * T_LEN] =
                (pool[df][i] + fmaxf(p0, 0.f)) * (1.0f / 21.0f);
        }
}

// ---------------------------------------------------------------------------
// k_mstcn R15: split-K waves + rotation swizzle + aliased H.
// R14 post-mortem: MfmaUtil 6.7 / VALUBusy 6.3 / HBM 2.7% -> pure exposed
// latency. Wave count was structurally capped at 16/CU (wave owns 16 t).
// Fix: 512-thr blocks, 8 waves; wave (qh, tg) computes channel-half qh of
// t-group tg -> per-wave work halves, 32 waves/CU (100% cap). qh0 hands
// partial C-tiles to qh1 via one LDS f32 buffer (+2 barriers; qh0 has no
// barriers after handoff so early-return is safe). Bank conflicts (1.97M,
// stride-144B rows): rotation swizzle col=(ch+row*8)&63 on X and H planes
// (wrap-safe for all 8/4/2-f16 chunks, 16B alignment kept). H+RED alias
// the dead X region: LDS 45->34KB, 4 blocks/CU at 512 thr.
// ---------------------------------------------------------------------------
template <bool FINAL>
__global__ __launch_bounds__(512, 8) void k_mstcn(
    const float* __restrict__ in,   // [B][64][T]
    const float* __restrict__ bs, const float* __restrict__ bm,
    const float* __restrict__ bl, const float* __restrict__ bo,
    int pkoff,                      // layer * 61440 (f16 units)
    float* __restrict__ out,        // [B][64][T]  (FINAL=false)
    const float* __restrict__ bd,   // [32]        (FINAL=true)
    float* __restrict__ outp)       // [B][32]     (FINAL=true)
{
    // f16 units: XH [0,6912) 96x72, XL [6912,13824).
    // After GEMM1 (X dead): RED 4096 f32 = [0,8192); HH [8192,12800) 64x72;
    // HL [12800,17408). Total 17408 f16 = 34816 B.
    __shared__ __align__(16) f16 lds[17408];

    const int b   = blockIdx.y;
    const int t0  = blockIdx.x * 64;
    const int tid = threadIdx.x;
    const float* inb = in + (long)b * 64 * T_LEN;

    // ---- stage x [t0-32, t0+64) -> rotated transposed hi/lo planes ----
    {
        const int c0 = (tid >> 4) * 2;      // channel pair
        const int tq = (tid & 15) * 6;      // 6 rows per thread
        float v0[6], v1[6];
        if (t0 != 0 || tq >= 32) {
            const float* r0 = inb + (long)c0 * T_LEN + (t0 - 32 + tq);
            const float* r1 = r0 + T_LEN;
            #pragma unroll
            for (int m = 0; m < 3; ++m) {
                *(float2*)(v0 + 2 * m) = *(const float2*)(r0 + 2 * m);
                *(float2*)(v1 + 2 * m) = *(const float2*)(r1 + 2 * m);
            }
        } else {
            #pragma unroll
            for (int i = 0; i < 6; ++i) {
                const int tg = tq + i - 32;
                v0[i] = (tg >= 0) ? inb[(long)c0 * T_LEN + tg] : 0.f;
                v1[i] = (tg >= 0) ? inb[(long)(c0 + 1) * T_LEN + tg] : 0.f;
            }
        }
        #pragma unroll
        for (int i = 0; i < 6; ++i) {
            const int row = tq + i;
            const int col = (c0 + row * 8) & 63;     // rotation swizzle
            const f16 h0 = (f16)v0[i], h1 = (f16)v1[i];
            *(f16x2*)(&lds[row * 72 + col]) = (f16x2){h0, h1};
            *(f16x2*)(&lds[6912 + row * 72 + col]) =
                (f16x2){(f16)(v0[i] - (float)h0), (f16)(v1[i] - (float)h1)};
        }
    }
    __syncthreads();                         // b1

    const int lane = tid & 63, wid = tid >> 6;
    const int qh  = wid >> 2;                // channel half (K-split)
    const int tg  = wid & 3;                 // t-group
    const int tw  = tg * 16;
    const int l15 = lane & 15, lg = lane >> 4;
    const f16* pk = g_pk + pkoff;
    const int la8 = lane * 8;

#define MFMA3(ACC, PA, BH, BL) do {                                        \
        const f16x8 ah_ = *(const f16x8*)(PA);                             \
        const f16x8 al_ = *(const f16x8*)((PA) + 512);                     \
        ACC = __builtin_amdgcn_mfma_f32_16x16x32_f16(ah_, BH, ACC, 0,0,0); \
        ACC = __builtin_amdgcn_mfma_f32_16x16x32_f16(ah_, BL, ACC, 0,0,0); \
        ACC = __builtin_amdgcn_mfma_f32_16x16x32_f16(al_, BH, ACC, 0,0,0); \
    } while (0)

#define BRD(BH, BL, ROW) do {                                              \
        const int r_ = (ROW);                                              \
        const int col_ = ((qh * 32 + lg * 8) + r_ * 8) & 63;               \
        BH = *(const f16x8*)(&lds[r_ * 72 + col_]);                        \
        BL = *(const f16x8*)(&lds[6912 + r_ * 72 + col_]);                 \
    } while (0)

    // ---- GEMM1: branches, channel-half qh only. C[j][t] ----
    f32x4 aS  = {0.f, 0.f, 0.f, 0.f};
    f32x4 aM  = {0.f, 0.f, 0.f, 0.f};
    f32x4 aL0 = {0.f, 0.f, 0.f, 0.f};
    f32x4 aL1 = {0.f, 0.f, 0.f, 0.f};

    #pragma unroll
    for (int kp = 0; kp < 3; ++kp) {
        f16x8 bh, bv; BRD(bh, bv, 30 + tw + l15 + kp);
        MFMA3(aS, pk + (2 * kp + qh) * 1024 + la8, bh, bv);
    }
    #pragma unroll
    for (int kp = 0; kp < 5; ++kp) {
        f16x8 bh, bv; BRD(bh, bv, 24 + tw + l15 + 2 * kp);
        MFMA3(aM, pk + (6 + 2 * kp + qh) * 1024 + la8, bh, bv);
    }
    #pragma unroll
    for (int kp = 0; kp < 9; ++kp) {
        f16x8 bh, bv; BRD(bh, bv, tw + l15 + 4 * kp);
        MFMA3(aL0, pk + (16 + 4 * kp + 2 * qh) * 1024 + la8, bh, bv);
        MFMA3(aL1, pk + (16 + 4 * kp + 2 * qh + 1) * 1024 + la8, bh, bv);
    }

    __syncthreads();                         // b2: X dead, RED/H live
    {
        float* red = (float*)lds;
        if (qh == 0) {
            float* rp = red + (tg * 64 + lane) * 16;
            *(f32x4*)(rp + 0)  = aS;
            *(f32x4*)(rp + 4)  = aM;
            *(f32x4*)(rp + 8)  = aL0;
            *(f32x4*)(rp + 12) = aL1;
        }
        __syncthreads();                     // b3: last barrier (qh0 may exit)
        if (qh == 0) return;
        const float* rp = red + (tg * 64 + lane) * 16;
        aS  += *(const f32x4*)(rp + 0);
        aM  += *(const f32x4*)(rp + 4);
        aL0 += *(const f32x4*)(rp + 8);
        aL1 += *(const f32x4*)(rp + 12);
    }

    // ---- bias (+relu) + hi/lo stage into rotated H planes [t][j] ----
#define STAGEH(ACC, BPTR, JB, RELU) do {                                   \
        const float4 bv_ = *(const float4*)(BPTR);                         \
        float x0_ = ACC[0] + bv_.x, x1_ = ACC[1] + bv_.y,                  \
              x2_ = ACC[2] + bv_.z, x3_ = ACC[3] + bv_.w;                  \
        if (RELU) { x0_ = fmaxf(x0_, 0.f); x1_ = fmaxf(x1_, 0.f);          \
                    x2_ = fmaxf(x2_, 0.f); x3_ = fmaxf(x3_, 0.f); }        \
        const f16 h0_ = (f16)x0_, h1_ = (f16)x1_;                          \
        const f16 h2_ = (f16)x2_, h3_ = (f16)x3_;                          \
        const int row_ = tw + l15;                                         \
        const int col_ = (((JB) + lg * 4) + row_ * 8) & 63;                \
        *(f16x2*)(&lds[8192 + row_ * 72 + col_])      = (f16x2){h0_, h1_}; \
        *(f16x2*)(&lds[8192 + row_ * 72 + col_ + 2])  = (f16x2){h2_, h3_}; \
        *(f16x2*)(&lds[12800 + row_ * 72 + col_])     =                    \
            (f16x2){(f16)(x0_ - (float)h0_), (f16)(x1_ - (float)h1_)};     \
        *(f16x2*)(&lds[12800 + row_ * 72 + col_ + 2]) =                    \
            (f16x2){(f16)(x2_ - (float)h2_), (f16)(x3_ - (float)h3_)};     \
    } while (0)

    STAGEH(aS,  bs + lg * 4,       0,  true);
    STAGEH(aM,  bm + lg * 4,       16, true);
    STAGEH(aL0, bl + lg * 4,       32, true);
    STAGEH(aL1, bl + 16 + lg * 4,  48, true);
    // no barrier: wave reads only its own 16 H rows below

#define HRD(BH, BL, KH) do {                                               \
        const int r_ = tw + l15;                                           \
        const int col_ = (((KH) * 32 + lg * 8) + r_ * 8) & 63;             \
        BH = *(const f16x8*)(&lds[8192 + r_ * 72 + col_]);                 \
        BL = *(const f16x8*)(&lds[12800 + r_ * 72 + col_]);                \
    } while (0)

    // ---- GEMM2: conv_out 64->64.  C[d][t] ----
    f32x4 o0 = {0.f, 0.f, 0.f, 0.f};
    f32x4 o1 = {0.f, 0.f, 0.f, 0.f};
    f32x4 o2 = {0.f, 0.f, 0.f, 0.f};
    f32x4 o3 = {0.f, 0.f, 0.f, 0.f};
    #pragma unroll
    for (int kh = 0; kh < 2; ++kh) {
        f16x8 bh, bv; HRD(bh, bv, kh);
        MFMA3(o0, pk + (52 + 0 + kh) * 1024 + la8, bh, bv);
        MFMA3(o1, pk + (52 + 2 + kh) * 1024 + la8, bh, bv);
        MFMA3(o2, pk + (52 + 4 + kh) * 1024 + la8, bh, bv);
        MFMA3(o3, pk + (52 + 6 + kh) * 1024 + la8, bh, bv);
    }

    if (!FINAL) {
        float* ob = out + (long)b * 64 * T_LEN + t0 + tw + l15;
        const float4 b0v = *(const float4*)(bo + lg * 4);
        const float4 b1v = *(const float4*)(bo + 16 + lg * 4);
        const float4 b2v = *(const float4*)(bo + 32 + lg * 4);
        const float4 b3v = *(const float4*)(bo + 48 + lg * 4);
#define STO4(ACC, BV, MS) do {                                             \
        ob[((MS) * 16 + lg * 4 + 0) * (long)T_LEN] = ACC[0] + BV.x;        \
        ob[((MS) * 16 + lg * 4 + 1) * (long)T_LEN] = ACC[1] + BV.y;        \
        ob[((MS) * 16 + lg * 4 + 2) * (long)T_LEN] = ACC[2] + BV.z;        \
        ob[((MS) * 16 + lg * 4 + 3) * (long)T_LEN] = ACC[3] + BV.w;        \
    } while (0)
        STO4(o0, b0v, 0);
        STO4(o1, b1v, 1);
        STO4(o2, b2v, 2);
        STO4(o3, b3v, 3);
#undef STO4
    } else {
        // ---- stage t2 (conv_out + bo, no relu); same rows -> wave-local ----
        STAGEH(o0, bo + lg * 4,       0,  false);
        STAGEH(o1, bo + 16 + lg * 4,  16, false);
        STAGEH(o2, bo + 32 + lg * 4,  32, false);
        STAGEH(o3, bo + 48 + lg * 4,  48, false);

        // ---- GEMM3: dense 64->32.  C[e][t] ----
        f32x4 e0 = {0.f, 0.f, 0.f, 0.f};
        f32x4 e1 = {0.f, 0.f, 0.f, 0.f};
        #pragma unroll
        for (int kh = 0; kh < 2; ++kh) {
            f16x8 bh, bv; HRD(bh, bv, kh);
            MFMA3(e0, g_pk + (120 + 0 + kh) * 1024 + la8, bh, bv);
            MFMA3(e1, g_pk + (120 + 2 + kh) * 1024 + la8, bh, bv);
        }
        const float4 bd0 = *(const float4*)(bd + lg * 4);
        const float4 bd1 = *(const float4*)(bd + 16 + lg * 4);
        const float cI = 1.0f / (float)T_LEN;
        float u0 = tanhf(e0[0] + bd0.x) * cI;
        float u1 = tanhf(e0[1] + bd0.y) * cI;
        float u2 = tanhf(e0[2] + bd0.z) * cI;
        float u3 = tanhf(e0[3] + bd0.w) * cI;
        float u4 = tanhf(e1[0] + bd1.x) * cI;
        float u5 = tanhf(e1[1] + bd1.y) * cI;
        float u6 = tanhf(e1[2] + bd1.z) * cI;
        float u7 = tanhf(e1[3] + bd1.w) * cI;
#define RED(U) do { U += __shfl_xor(U, 1); U += __shfl_xor(U, 2);          \
                    U += __shfl_xor(U, 4); U += __shfl_xor(U, 8); } while (0)
        RED(u0); RED(u1); RED(u2); RED(u3);
        RED(u4); RED(u5); RED(u6); RED(u7);
#undef RED
        if (l15 == 0) {
            float* op = outp + b * 32;
            atomicAdd(op + lg * 4 + 0, u0);
            atomicAdd(op + lg * 4 + 1, u1);
            atomicAdd(op + lg * 4 + 2, u2);
            atomicAdd(op + lg * 4 + 3, u3);
            atomicAdd(op + 16 + lg * 4 + 0, u4);
            atomicAdd(op + 16 + lg * 4 + 1, u5);
            atomicAdd(op + 16 + lg * 4 + 2, u6);
            atomicAdd(op + 16 + lg * 4 + 3, u7);
        }
    }
#undef HRD
#undef STAGEH
#undef BRD
#undef MFMA3
}

extern "C" void kernel_launch(void* const* d_in, const int* in_sizes, int n_in,
                              void* d_out, int out_size, void* d_ws, size_t ws_size,
                              hipStream_t stream) {
    const float* x     = (const float*)d_in[0];
    const float* gcn_w = (const float*)d_in[1];
    const float* wd    = (const float*)d_in[2];
    const float* bd    = (const float*)d_in[3];
    const float* t1_ws = (const float*)d_in[4];
    const float* t1_bs = (const float*)d_in[5];
    const float* t1_wm = (const float*)d_in[6];
    const float* t1_bm = (const float*)d_in[7];
    const float* t1_wl = (const float*)d_in[8];
    const float* t1_bl = (const float*)d_in[9];
    const float* t1_wo = (const float*)d_in[10];
    const float* t1_bo = (const float*)d_in[11];
    const float* t2_ws = (const float*)d_in[12];
    const float* t2_bs = (const float*)d_in[13];
    const float* t2_wm = (const float*)d_in[14];
    const float* t2_bm = (const float*)d_in[15];
    const float* t2_wl = (const float*)d_in[16];
    const float* t2_bl = (const float*)d_in[17];
    const float* t2_wo = (const float*)d_in[18];
    const float* t2_bo = (const float*)d_in[19];

    float* b0 = (float*)d_ws;                          // [16][64][4096]
    float* b1 = b0 + (size_t)BATCH * 64 * T_LEN;       // [16][64][4096]

    hipMemsetAsync(d_out, 0, (size_t)out_size * sizeof(float), stream);

    k_pack<<<dim3(132), 256, 0, stream>>>(
        t1_ws, t1_wm, t1_wl, t1_wo, t2_ws, t2_wm, t2_wl, t2_wo, wd, gcn_w);

    k_gcn<<<dim3(T_LEN / 64, BATCH), 256, 0, stream>>>(x, b0);

    k_mstcn<false><<<dim3(T_LEN / 64, BATCH), 512, 0, stream>>>(
        b0, t1_bs, t1_bm, t1_bl, t1_bo, 0,
        b1, nullptr, nullptr);

    k_mstcn<true><<<dim3(T_LEN / 64, BATCH), 512, 0, stream>>>(
        b1, t2_bs, t2_bm, t2_bl, t2_bo, 61440,
        nullptr, bd, (float*)d_out);
}

// Round 8
// 202.008 us; speedup vs baseline: 3.2421x; 1.1862x over previous
//
#include <hip/hip_runtime.h>
#include <hip/hip_bf16.h>
#include <math.h>

#define T_LEN 4096
#define BATCH 16

typedef _Float16 f16;
typedef _Float16 f16x2 __attribute__((ext_vector_type(2)));
typedef _Float16 f16x8 __attribute__((ext_vector_type(8)));
typedef float f32x4 __attribute__((ext_vector_type(4)));

// Packed MFMA A-fragments, hi/lo split-f16. 132 logical frags:
// per layer (60): S[k(3)][q(2)]=0..5, M[k(5)][q(2)]=6..15,
// L[k(9)][q(2)][ms(2)]=16..51, O[ms(4)][kh(2)]=52..59; layer stride 60.
// D (dense 64->32): 120..123 = [ms(2)][kh(2)].
// GCN: 124..127 = bone proj A[df]; 128..131 = palm proj A[df].
// Frag f: hi at f*1024 + lane*8, lo at f*1024 + 512 + lane*8 (f16 units).
// A[m][k]: m = lane&15, k = (lane>>4)*8 + j  (16x16x32 f16 A-layout).
__device__ __align__(16) f16 g_pk[132 * 1024];

// ---------------------------------------------------------------------------
// k_pack: one-time weight repack -> MFMA fragments (hi/lo f16). (unchanged)
// ---------------------------------------------------------------------------
__global__ void k_pack(
    const float* __restrict__ ws1, const float* __restrict__ wm1,
    const float* __restrict__ wl1, const float* __restrict__ wo1,
    const float* __restrict__ ws2, const float* __restrict__ wm2,
    const float* __restrict__ wl2, const float* __restrict__ wo2,
    const float* __restrict__ wd,  const float* __restrict__ gcn_w)
{
    const int g = blockIdx.x;          // 0..131 logical frag
    const int tid = threadIdx.x;
    #pragma unroll
    for (int u = 0; u < 2; ++u) {
        const int e = tid * 2 + u;     // 0..511
        const int lane = e >> 3, j = e & 7;
        const int m = lane & 15, k = (lane >> 4) * 8 + j;
        float w;
        if (g < 120) {
            const int layer = g / 60, r0 = g % 60;
            const float* pws = layer ? ws2 : ws1;
            const float* pwm = layer ? wm2 : wm1;
            const float* pwl = layer ? wl2 : wl1;
            const float* pwo = layer ? wo2 : wo1;
            if (r0 < 6) {
                const int kp = r0 >> 1, q = r0 & 1;
                w = pws[(kp * 64 + q * 32 + k) * 16 + m];        // ws[k][c][j]
            } else if (r0 < 16) {
                const int r = r0 - 6, kp = r >> 1, q = r & 1;
                w = pwm[(kp * 64 + q * 32 + k) * 16 + m];
            } else if (r0 < 52) {
                const int r = r0 - 16, kp = r >> 2, q = (r >> 1) & 1, ms = r & 1;
                w = pwl[(kp * 64 + q * 32 + k) * 32 + ms * 16 + m];
            } else {
                const int r = r0 - 52, ms = r >> 1, kh = r & 1;
                w = pwo[(kh * 32 + k) * 64 + ms * 16 + m];       // wo[j][d] -> A[d][j]
            }
        } else if (g < 124) {
            const int r = g - 120, ms = r >> 1, kh = r & 1;
            w = wd[(kh * 32 + k) * 32 + ms * 16 + m];            // wd[d][e] -> A[e][d]
        } else {
            const int r = g - 124, df = r & 3;
            const int lim = (r >> 2) ? 18 : 10;                  // palm : bone
            w = (k < lim) ? gcn_w[k * 64 + df * 16 + m] : 0.f;
        }
        const f16 hi = (f16)w;
        const f16 lo = (f16)(w - (float)hi);
        g_pk[g * 1024 + e] = hi;
        g_pk[g * 1024 + 512 + e] = lo;
    }
}

__device__ inline f32x4 mfma3z(f16x8 ah, f16x8 al, f16x8 bh, f16x8 bl) {
    f32x4 a = {0.f, 0.f, 0.f, 0.f};
    a = __builtin_amdgcn_mfma_f32_16x16x32_f16(ah, bh, a, 0, 0, 0);
    a = __builtin_amdgcn_mfma_f32_16x16x32_f16(ah, bl, a, 0, 0, 0);
    a = __builtin_amdgcn_mfma_f32_16x16x32_f16(al, bh, a, 0, 0, 0);
    return a;
}

// ---------------------------------------------------------------------------
// k_gcn R14: MFMA rewrite. (unchanged - no longer in top-5)
// ---------------------------------------------------------------------------
__global__ __launch_bounds__(256) void k_gcn(
    const float* __restrict__ x,      // [B][T][218]
    float* __restrict__ hp)           // [B][64][T]
{
    const int b   = blockIdx.y;
    const int t0  = blockIdx.x * 64;
    const int tid = threadIdx.x;
    const int lane = tid & 63, wid = tid >> 6;
    const int l15 = lane & 15, lg = lane >> 4;
    const int t = t0 + wid * 16 + l15;
    const float* xrow = x + ((long)b * T_LEN + t) * 218;
    const int la8 = lane * 8;

    const float cP = 1.0f / 6.0f;
    const float cS = 0.23570226039551584f;   // 1/sqrt(18)
    const float c3 = 1.0f / 3.0f;
    const float cT = 0.4082482904638631f;    // 1/sqrt(6)
    const float cH = 0.5f;

    // ---- palm: h0 = x[0:18] . gcn_w  (K-pad lanes read ch16..23, A=0) ----
    f32x4 h0[4];
    {
        float vv[8];
        const int po = (lg < 2) ? lg * 8 : 16;
        *(float2*)(vv + 0) = *(const float2*)(xrow + po);
        *(float2*)(vv + 2) = *(const float2*)(xrow + po + 2);
        *(float2*)(vv + 4) = *(const float2*)(xrow + po + 4);
        *(float2*)(vv + 6) = *(const float2*)(xrow + po + 6);
        f16x8 bh, bl;
        #pragma unroll
        for (int j = 0; j < 8; ++j) {
            const f16 h = (f16)vv[j];
            bh[j] = h; bl[j] = (f16)(vv[j] - (float)h);
        }
        #pragma unroll
        for (int df = 0; df < 4; ++df) {
            const f16x8 ah = *(const f16x8*)(g_pk + (128 + df) * 1024 + la8);
            const f16x8 al = *(const f16x8*)(g_pk + (128 + df) * 1024 + 512 + la8);
            h0[df] = mfma3z(ah, al, bh, bl);
        }
    }

    // ---- bone projection A-frags: register-resident, shared by all 20 ----
    f16x8 Abh[4], Abl[4];
    #pragma unroll
    for (int df = 0; df < 4; ++df) {
        Abh[df] = *(const f16x8*)(g_pk + (124 + df) * 1024 + la8);
        Abl[df] = *(const f16x8*)(g_pk + (124 + df) * 1024 + 512 + la8);
    }

    f32x4 pool[4], star[4], s12[4], hprev[4];
    #pragma unroll
    for (int df = 0; df < 4; ++df) {
        pool[df] = (f32x4){0.f, 0.f, 0.f, 0.f};
        star[df] = (f32x4){0.f, 0.f, 0.f, 0.f};
    }

    #pragma unroll 1
    for (int f = 0; f < 5; ++f) {
        #pragma unroll
        for (int n = 0; n < 4; ++n) {
            const int w = 4 * f + n;
            const float* bp = xrow + 18 + 10 * w;
            float vv[8];
            const bool g0 = (lg == 0);
            *(float2*)(vv + 0) = *(const float2*)(bp + ((lg == 1) ? 8 : 0));
            *(float2*)(vv + 2) = *(const float2*)(bp + (g0 ? 2 : 0));
            *(float2*)(vv + 4) = *(const float2*)(bp + (g0 ? 4 : 0));
            *(float2*)(vv + 6) = *(const float2*)(bp + (g0 ? 6 : 0));
            f16x8 bh, bl;
            #pragma unroll
            for (int j = 0; j < 8; ++j) {
                const f16 h = (f16)vv[j];
                bh[j] = h; bl[j] = (f16)(vv[j] - (float)h);
            }
            f32x4 hn[4];
            #pragma unroll
            for (int df = 0; df < 4; ++df)
                hn[df] = mfma3z(Abh[df], Abl[df], bh, bl);

            #pragma unroll
            for (int df = 0; df < 4; ++df)
                #pragma unroll
                for (int i = 0; i < 4; ++i) {
                    const float h = hn[df][i];
                    if (n == 0) {
                        star[df][i] += h;
                        s12[df][i] = h;
                        hprev[df][i] = h;
                    } else if (n == 1) {
                        const float pa = fmaf(cS, h0[df][i], c3 * (s12[df][i] + h));
                        pool[df][i] += fmaxf(pa, 0.f);
                        s12[df][i] += h;
                        hprev[df][i] = h;
                    } else if (n == 2) {
                        const float pb = c3 * (s12[df][i] + h);
                        pool[df][i] += fmaxf(pb, 0.f);
                        s12[df][i] = hprev[df][i] + h;
                        hprev[df][i] = h;
                    } else {
                        const float pc = fmaf(cT, h, c3 * s12[df][i]);
                        const float pe = fmaf(cT, hprev[df][i], cH * h);
                        pool[df][i] += fmaxf(pc, 0.f) + fmaxf(pe, 0.f);
                    }
                }
        }
    }

    float* hpb = hp + (long)b * 64 * T_LEN + t;
    #pragma unroll
    for (int df = 0; df < 4; ++df)
        #pragma unroll
        for (int i = 0; i < 4; ++i) {
            const float p0 = fmaf(cP, h0[df][i], cS * star[df][i]);
            hpb[(long)(df * 16 + lg * 4 + i) * T_LEN] =
                (pool[df][i] + fmaxf(p0, 0.f)) * (1.0f / 21.0f);
        }
}

// ---------------------------------------------------------------------------
// k_mstcn R16: register relief + A-fragment amortization.
// R15 post-mortem: VGPR_Count=32 (launch_bounds(512,8) strangled the
// allocator; 4 accs + A + B = 32 regs, zero left -> no pk prefetch, every
// trio eats a full L2 round-trip). Bank conflicts DOUBLED (4.0M): the
// rotation swizzle made read-lane spacing 160B = 32 mod 128 (4-way) and
// the RED layout had 64B lane stride (32-way on every f32x4).
// Fixes: (a) launch_bounds(512,4) -> 128 VGPR budget, compiler can
// pipeline pk loads (the thing it does well, cf R8 weights); (b) block
// tile 128 t, wave owns 32 t as 2 subtiles -> each A-frag load feeds 2x
// the MFMAs, pk traffic halved; (c) linear (unswizzled) X/H layout
// (144B row stride = 16 mod 128 = ~2-way, near-free); (d) RED slot-major:
// slot*1024 + (tg*64+lane)*4 floats = 16B lane stride, conflict-free.
// LDS 69.6KB -> 2 blocks/CU = 16 waves/CU with real ILP.
// ---------------------------------------------------------------------------
template <bool FINAL>
__global__ __launch_bounds__(512, 4) void k_mstcn(
    const float* __restrict__ in,   // [B][64][T]
    const float* __restrict__ bs, const float* __restrict__ bm,
    const float* __restrict__ bl, const float* __restrict__ bo,
    int pkoff,                      // layer * 61440 (f16 units)
    float* __restrict__ out,        // [B][64][T]  (FINAL=false)
    const float* __restrict__ bd,   // [32]        (FINAL=true)
    float* __restrict__ outp)       // [B][32]     (FINAL=true)
{
    // f16 units: XH [0,11520) = 160 rows x 72;  XL [11520,23040).
    // After GEMM1 (X dead): RED 8192 f32 = units [0,16384);
    // HH [16384,25600) = 128 x 72; HL [25600,34816). Total 69632 B.
    __shared__ __align__(16) f16 lds[34816];

    const int b   = blockIdx.y;
    const int t0  = blockIdx.x * 128;
    const int tid = threadIdx.x;
    const float* inb = in + (long)b * 64 * T_LEN;

    // ---- stage x [t0-32, t0+128) -> transposed hi/lo planes (linear) ----
    {
        const int c0 = (tid >> 4) * 2;      // channel pair 0..62
        const int tq = (tid & 15) * 10;     // 10 rows per thread
        float v0[10], v1[10];
        if (t0 != 0 || tq >= 40) {
            const float* r0 = inb + (long)c0 * T_LEN + (t0 - 32 + tq);
            const float* r1 = r0 + T_LEN;
            #pragma unroll
            for (int m = 0; m < 5; ++m) {
                *(float2*)(v0 + 2 * m) = *(const float2*)(r0 + 2 * m);
                *(float2*)(v1 + 2 * m) = *(const float2*)(r1 + 2 * m);
            }
        } else {
            #pragma unroll
            for (int i = 0; i < 10; ++i) {
                const int tg_ = tq + i - 32;
                v0[i] = (tg_ >= 0) ? inb[(long)c0 * T_LEN + tg_] : 0.f;
                v1[i] = (tg_ >= 0) ? inb[(long)(c0 + 1) * T_LEN + tg_] : 0.f;
            }
        }
        #pragma unroll
        for (int i = 0; i < 10; ++i) {
            const int row = tq + i;
            const f16 h0 = (f16)v0[i], h1 = (f16)v1[i];
            *(f16x2*)(&lds[row * 72 + c0]) = (f16x2){h0, h1};
            *(f16x2*)(&lds[11520 + row * 72 + c0]) =
                (f16x2){(f16)(v0[i] - (float)h0), (f16)(v1[i] - (float)h1)};
        }
    }
    __syncthreads();                         // b1

    const int lane = tid & 63, wid = tid >> 6;
    const int qh  = wid >> 2;                // channel half (K-split)
    const int tg  = wid & 3;                 // t-group (32 t each)
    const int l15 = lane & 15, lg = lane >> 4;
    const int tws0 = tg * 32, tws1 = tg * 32 + 16;
    const f16* pk = g_pk + pkoff;
    const int la8 = lane * 8;

#define MFMA3(ACC, AH, AL, BH, BL) do {                                    \
        ACC = __builtin_amdgcn_mfma_f32_16x16x32_f16(AH, BH, ACC, 0,0,0);  \
        ACC = __builtin_amdgcn_mfma_f32_16x16x32_f16(AH, BL, ACC, 0,0,0);  \
        ACC = __builtin_amdgcn_mfma_f32_16x16x32_f16(AL, BH, ACC, 0,0,0);  \
    } while (0)

#define LOADA(AH, AL, FR) do {                                             \
        AH = *(const f16x8*)(pk + (FR) * 1024 + la8);                      \
        AL = *(const f16x8*)(pk + (FR) * 1024 + 512 + la8);                \
    } while (0)

#define BRD(BH, BL, ROW) do {                                              \
        const int r_ = (ROW);                                              \
        BH = *(const f16x8*)(&lds[r_ * 72 + qh * 32 + lg * 8]);            \
        BL = *(const f16x8*)(&lds[11520 + r_ * 72 + qh * 32 + lg * 8]);    \
    } while (0)

    // ---- GEMM1: branches, channel-half qh, 2 t-subtiles. C[j][t] ----
    f32x4 aS0 = {0.f,0.f,0.f,0.f}, aS1 = {0.f,0.f,0.f,0.f};
    f32x4 aM0 = {0.f,0.f,0.f,0.f}, aM1 = {0.f,0.f,0.f,0.f};
    f32x4 aL00 = {0.f,0.f,0.f,0.f}, aL01 = {0.f,0.f,0.f,0.f};
    f32x4 aL10 = {0.f,0.f,0.f,0.f}, aL11 = {0.f,0.f,0.f,0.f};

    #pragma unroll
    for (int kp = 0; kp < 3; ++kp) {
        f16x8 ah, al, bh, bv;
        LOADA(ah, al, 2 * kp + qh);
        BRD(bh, bv, 30 + tws0 + l15 + kp); MFMA3(aS0, ah, al, bh, bv);
        BRD(bh, bv, 30 + tws1 + l15 + kp); MFMA3(aS1, ah, al, bh, bv);
    }
    #pragma unroll
    for (int kp = 0; kp < 5; ++kp) {
        f16x8 ah, al, bh, bv;
        LOADA(ah, al, 6 + 2 * kp + qh);
        BRD(bh, bv, 24 + tws0 + l15 + 2 * kp); MFMA3(aM0, ah, al, bh, bv);
        BRD(bh, bv, 24 + tws1 + l15 + 2 * kp); MFMA3(aM1, ah, al, bh, bv);
    }
    #pragma unroll
    for (int kp = 0; kp < 9; ++kp) {
        f16x8 a0h, a0l, a1h, a1l, bh, bv;
        LOADA(a0h, a0l, 16 + 4 * kp + 2 * qh);
        LOADA(a1h, a1l, 16 + 4 * kp + 2 * qh + 1);
        BRD(bh, bv, tws0 + l15 + 4 * kp);
        MFMA3(aL00, a0h, a0l, bh, bv); MFMA3(aL10, a1h, a1l, bh, bv);
        BRD(bh, bv, tws1 + l15 + 4 * kp);
        MFMA3(aL01, a0h, a0l, bh, bv); MFMA3(aL11, a1h, a1l, bh, bv);
    }

    __syncthreads();                         // b2: X dead, RED live
    {
        float* red = (float*)lds;
        const int ro = (tg * 64 + lane) * 4; // 16B lane stride: conflict-free
        if (qh == 0) {
            *(f32x4*)(red + 0 * 1024 + ro) = aS0;
            *(f32x4*)(red + 1 * 1024 + ro) = aM0;
            *(f32x4*)(red + 2 * 1024 + ro) = aL00;
            *(f32x4*)(red + 3 * 1024 + ro) = aL10;
            *(f32x4*)(red + 4 * 1024 + ro) = aS1;
            *(f32x4*)(red + 5 * 1024 + ro) = aM1;
            *(f32x4*)(red + 6 * 1024 + ro) = aL01;
            *(f32x4*)(red + 7 * 1024 + ro) = aL11;
        }
        __syncthreads();                     // b3: last barrier (qh0 exits)
        if (qh == 0) return;
        aS0  += *(const f32x4*)(red + 0 * 1024 + ro);
        aM0  += *(const f32x4*)(red + 1 * 1024 + ro);
        aL00 += *(const f32x4*)(red + 2 * 1024 + ro);
        aL10 += *(const f32x4*)(red + 3 * 1024 + ro);
        aS1  += *(const f32x4*)(red + 4 * 1024 + ro);
        aM1  += *(const f32x4*)(red + 5 * 1024 + ro);
        aL01 += *(const f32x4*)(red + 6 * 1024 + ro);
        aL11 += *(const f32x4*)(red + 7 * 1024 + ro);
    }

    // ---- bias (+relu) + hi/lo stage into H planes [t][j] (linear) ----
#define STAGEH(ACC, BPTR, JB, RELU, RB) do {                               \
        const float4 bv_ = *(const float4*)(BPTR);                         \
        float x0_ = ACC[0] + bv_.x, x1_ = ACC[1] + bv_.y,                  \
              x2_ = ACC[2] + bv_.z, x3_ = ACC[3] + bv_.w;                  \
        if (RELU) { x0_ = fmaxf(x0_, 0.f); x1_ = fmaxf(x1_, 0.f);          \
                    x2_ = fmaxf(x2_, 0.f); x3_ = fmaxf(x3_, 0.f); }        \
        const f16 h0_ = (f16)x0_, h1_ = (f16)x1_;                          \
        const f16 h2_ = (f16)x2_, h3_ = (f16)x3_;                          \
        const int ro_ = ((RB) + l15) * 72 + (JB) + lg * 4;                 \
        *(f16x2*)(&lds[16384 + ro_])     = (f16x2){h0_, h1_};              \
        *(f16x2*)(&lds[16384 + ro_ + 2]) = (f16x2){h2_, h3_};              \
        *(f16x2*)(&lds[25600 + ro_])     =                                 \
            (f16x2){(f16)(x0_ - (float)h0_), (f16)(x1_ - (float)h1_)};     \
        *(f16x2*)(&lds[25600 + ro_ + 2]) =                                 \
            (f16x2){(f16)(x2_ - (float)h2_), (f16)(x3_ - (float)h3_)};     \
    } while (0)

    STAGEH(aS0,  bs + lg * 4,       0,  true, tws0);
    STAGEH(aM0,  bm + lg * 4,       16, true, tws0);
    STAGEH(aL00, bl + lg * 4,       32, true, tws0);
    STAGEH(aL10, bl + 16 + lg * 4,  48, true, tws0);
    STAGEH(aS1,  bs + lg * 4,       0,  true, tws1);
    STAGEH(aM1,  bm + lg * 4,       16, true, tws1);
    STAGEH(aL01, bl + lg * 4,       32, true, tws1);
    STAGEH(aL11, bl + 16 + lg * 4,  48, true, tws1);
    // no barrier: wave reads only its own 32 H rows below

#define HRD(BH, BL, RB, KH) do {                                           \
        const int ro_ = ((RB) + l15) * 72 + (KH) * 32 + lg * 8;            \
        BH = *(const f16x8*)(&lds[16384 + ro_]);                           \
        BL = *(const f16x8*)(&lds[25600 + ro_]);                           \
    } while (0)

    // ---- GEMM2: conv_out 64->64.  C[d][t], 2 subtiles ----
    f32x4 oA0 = {0.f,0.f,0.f,0.f}, oA1 = {0.f,0.f,0.f,0.f};
    f32x4 oA2 = {0.f,0.f,0.f,0.f}, oA3 = {0.f,0.f,0.f,0.f};
    f32x4 oB0 = {0.f,0.f,0.f,0.f}, oB1 = {0.f,0.f,0.f,0.f};
    f32x4 oB2 = {0.f,0.f,0.f,0.f}, oB3 = {0.f,0.f,0.f,0.f};
    #pragma unroll
    for (int kh = 0; kh < 2; ++kh) {
        f16x8 b0h, b0l, b1h, b1l, ah, al;
        HRD(b0h, b0l, tws0, kh);
        HRD(b1h, b1l, tws1, kh);
        LOADA(ah, al, 52 + 0 + kh);
        MFMA3(oA0, ah, al, b0h, b0l); MFMA3(oB0, ah, al, b1h, b1l);
        LOADA(ah, al, 52 + 2 + kh);
        MFMA3(oA1, ah, al, b0h, b0l); MFMA3(oB1, ah, al, b1h, b1l);
        LOADA(ah, al, 52 + 4 + kh);
        MFMA3(oA2, ah, al, b0h, b0l); MFMA3(oB2, ah, al, b1h, b1l);
        LOADA(ah, al, 52 + 6 + kh);
        MFMA3(oA3, ah, al, b0h, b0l); MFMA3(oB3, ah, al, b1h, b1l);
    }

    if (!FINAL) {
        const float4 b0v = *(const float4*)(bo + lg * 4);
        const float4 b1v = *(const float4*)(bo + 16 + lg * 4);
        const float4 b2v = *(const float4*)(bo + 32 + lg * 4);
        const float4 b3v = *(const float4*)(bo + 48 + lg * 4);
#define STO4(ACC, BV, MS, OB) do {                                         \
        (OB)[((MS) * 16 + lg * 4 + 0) * (long)T_LEN] = ACC[0] + BV.x;      \
        (OB)[((MS) * 16 + lg * 4 + 1) * (long)T_LEN] = ACC[1] + BV.y;      \
        (OB)[((MS) * 16 + lg * 4 + 2) * (long)T_LEN] = ACC[2] + BV.z;      \
        (OB)[((MS) * 16 + lg * 4 + 3) * (long)T_LEN] = ACC[3] + BV.w;      \
    } while (0)
        float* obA = out + (long)b * 64 * T_LEN + t0 + tws0 + l15;
        float* obB = out + (long)b * 64 * T_LEN + t0 + tws1 + l15;
        STO4(oA0, b0v, 0, obA); STO4(oB0, b0v, 0, obB);
        STO4(oA1, b1v, 1, obA); STO4(oB1, b1v, 1, obB);
        STO4(oA2, b2v, 2, obA); STO4(oB2, b2v, 2, obB);
        STO4(oA3, b3v, 3, obA); STO4(oB3, b3v, 3, obB);
#undef STO4
    } else {
        // ---- stage t2 (conv_out + bo, no relu); wave-local rows ----
        STAGEH(oA0, bo + lg * 4,       0,  false, tws0);
        STAGEH(oA1, bo + 16 + lg * 4,  16, false, tws0);
        STAGEH(oA2, bo + 32 + lg * 4,  32, false, tws0);
        STAGEH(oA3, bo + 48 + lg * 4,  48, false, tws0);
        STAGEH(oB0, bo + lg * 4,       0,  false, tws1);
        STAGEH(oB1, bo + 16 + lg * 4,  16, false, tws1);
        STAGEH(oB2, bo + 32 + lg * 4,  32, false, tws1);
        STAGEH(oB3, bo + 48 + lg * 4,  48, false, tws1);

        // ---- GEMM3: dense 64->32.  C[e][t], 2 subtiles ----
        f32x4 eA0 = {0.f,0.f,0.f,0.f}, eA1 = {0.f,0.f,0.f,0.f};
        f32x4 eB0 = {0.f,0.f,0.f,0.f}, eB1 = {0.f,0.f,0.f,0.f};
        #pragma unroll
        for (int kh = 0; kh < 2; ++kh) {
            f16x8 b0h, b0l, b1h, b1l, ah, al;
            HRD(b0h, b0l, tws0, kh);
            HRD(b1h, b1l, tws1, kh);
            ah = *(const f16x8*)(g_pk + (120 + 0 + kh) * 1024 + la8);
            al = *(const f16x8*)(g_pk + (120 + 0 + kh) * 1024 + 512 + la8);
            MFMA3(eA0, ah, al, b0h, b0l); MFMA3(eB0, ah, al, b1h, b1l);
            ah = *(const f16x8*)(g_pk + (120 + 2 + kh) * 1024 + la8);
            al = *(const f16x8*)(g_pk + (120 + 2 + kh) * 1024 + 512 + la8);
            MFMA3(eA1, ah, al, b0h, b0l); MFMA3(eB1, ah, al, b1h, b1l);
        }
        const float4 bd0 = *(const float4*)(bd + lg * 4);
        const float4 bd1 = *(const float4*)(bd + 16 + lg * 4);
        const float cI = 1.0f / (float)T_LEN;
        float u0 = (tanhf(eA0[0] + bd0.x) + tanhf(eB0[0] + bd0.x)) * cI;
        float u1 = (tanhf(eA0[1] + bd0.y) + tanhf(eB0[1] + bd0.y)) * cI;
        float u2 = (tanhf(eA0[2] + bd0.z) + tanhf(eB0[2] + bd0.z)) * cI;
        float u3 = (tanhf(eA0[3] + bd0.w) + tanhf(eB0[3] + bd0.w)) * cI;
        float u4 = (tanhf(eA1[0] + bd1.x) + tanhf(eB1[0] + bd1.x)) * cI;
        float u5 = (tanhf(eA1[1] + bd1.y) + tanhf(eB1[1] + bd1.y)) * cI;
        float u6 = (tanhf(eA1[2] + bd1.z) + tanhf(eB1[2] + bd1.z)) * cI;
        float u7 = (tanhf(eA1[3] + bd1.w) + tanhf(eB1[3] + bd1.w)) * cI;
#define RED(U) do { U += __shfl_xor(U, 1); U += __shfl_xor(U, 2);          \
                    U += __shfl_xor(U, 4); U += __shfl_xor(U, 8); } while (0)
        RED(u0); RED(u1); RED(u2); RED(u3);
        RED(u4); RED(u5); RED(u6); RED(u7);
#undef RED
        if (l15 == 0) {
            float* op = outp + b * 32;
            atomicAdd(op + lg * 4 + 0, u0);
            atomicAdd(op + lg * 4 + 1, u1);
            atomicAdd(op + lg * 4 + 2, u2);
            atomicAdd(op + lg * 4 + 3, u3);
            atomicAdd(op + 16 + lg * 4 + 0, u4);
            atomicAdd(op + 16 + lg * 4 + 1, u5);
            atomicAdd(op + 16 + lg * 4 + 2, u6);
            atomicAdd(op + 16 + lg * 4 + 3, u7);
        }
    }
#undef HRD
#undef STAGEH
#undef BRD
#undef LOADA
#undef MFMA3
}

extern "C" void kernel_launch(void* const* d_in, const int* in_sizes, int n_in,
                              void* d_out, int out_size, void* d_ws, size_t ws_size,
                              hipStream_t stream) {
    const float* x     = (const float*)d_in[0];
    const float* gcn_w = (const float*)d_in[1];
    const float* wd    = (const float*)d_in[2];
    const float* bd    = (const float*)d_in[3];
    const float* t1_ws = (const float*)d_in[4];
    const float* t1_bs = (const float*)d_in[5];
    const float* t1_wm = (const float*)d_in[6];
    const float* t1_bm = (const float*)d_in[7];
    const float* t1_wl = (const float*)d_in[8];
    const float* t1_bl = (const float*)d_in[9];
    const float* t1_wo = (const float*)d_in[10];
    const float* t1_bo = (const float*)d_in[11];
    const float* t2_ws = (const float*)d_in[12];
    const float* t2_bs = (const float*)d_in[13];
    const float* t2_wm = (const float*)d_in[14];
    const float* t2_bm = (const float*)d_in[15];
    const float* t2_wl = (const float*)d_in[16];
    const float* t2_bl = (const float*)d_in[17];
    const float* t2_wo = (const float*)d_in[18];
    const float* t2_bo = (const float*)d_in[19];

    float* b0 = (float*)d_ws;                          // [16][64][4096]
    float* b1 = b0 + (size_t)BATCH * 64 * T_LEN;       // [16][64][4096]

    hipMemsetAsync(d_out, 0, (size_t)out_size * sizeof(float), stream);

    k_pack<<<dim3(132), 256, 0, stream>>>(
        t1_ws, t1_wm, t1_wl, t1_wo, t2_ws, t2_wm, t2_wl, t2_wo, wd, gcn_w);

    k_gcn<<<dim3(T_LEN / 64, BATCH), 256, 0, stream>>>(x, b0);

    k_mstcn<false><<<dim3(T_LEN / 128, BATCH), 512, 0, stream>>>(
        b0, t1_bs, t1_bm, t1_bl, t1_bo, 0,
        b1, nullptr, nullptr);

    k_mstcn<true><<<dim3(T_LEN / 128, BATCH), 512, 0, stream>>>(
        b1, t2_bs, t2_bm, t2_bl, t2_bo, 61440,
        nullptr, bd, (float*)d_out);
}